// Round 16
// baseline (185.011 us; speedup 1.0000x reference)
//
#include <hip/hip_runtime.h>

#define HEADS 8
#define Bq 4
#define Nq 2048
#define Dq 512
#define Hq 2048

typedef __bf16 bf16;
typedef __bf16 bf16x8 __attribute__((ext_vector_type(8)));
typedef __bf16 bf16x4 __attribute__((ext_vector_type(4)));
typedef short short4v __attribute__((ext_vector_type(4)));
typedef float f32x4 __attribute__((ext_vector_type(4)));

__device__ __forceinline__ void gload16(const bf16* g, bf16* s) {
  __builtin_amdgcn_global_load_lds(
      (const __attribute__((address_space(1))) void*)g,
      (__attribute__((address_space(3))) void*)s, 16, 0, 0);
}

__device__ __forceinline__ float fexp2(float x) {
#if __has_builtin(__builtin_amdgcn_exp2f)
  return __builtin_amdgcn_exp2f(x);
#else
  return exp2f(x);
#endif
}

// 16x16x16 bf16 MFMA (legacy shape; A/B = 4 bf16 = 2 VGPR, k = 4g..4g+3 per lane)
__device__ __forceinline__ f32x4 mfma16(bf16x4 a, bf16x4 b, f32x4 c) {
#if __has_builtin(__builtin_amdgcn_mfma_f32_16x16x16bf16_1k)
  return __builtin_amdgcn_mfma_f32_16x16x16bf16_1k(
      __builtin_bit_cast(short4v, a), __builtin_bit_cast(short4v, b), c, 0, 0, 0);
#else
  f32x4 d = c;
  asm("v_mfma_f32_16x16x16_bf16 %0, %1, %2, %0" : "+v"(d) : "v"(a), "v"(b));
  return d;
#endif
}

// counted-vmcnt barrier pair (attn only — helps there, hurts GEMM per R14 A/B)
#define VM_BARRIER(N)                                         \
  do {                                                        \
    asm volatile("s_waitcnt vmcnt(" #N ")" ::: "memory");     \
    __builtin_amdgcn_s_barrier();                             \
    asm volatile("" ::: "memory");                            \
  } while (0)
#define END_BARRIER()                                         \
  do {                                                        \
    asm volatile("" ::: "memory");                            \
    __builtin_amdgcn_s_barrier();                             \
    asm volatile("" ::: "memory");                            \
  } while (0)

// ---------------- fp32 -> bf16 elementwise convert ----------------
__global__ __launch_bounds__(256) void k_cvt_bf16(const float* __restrict__ in,
                                                  bf16* __restrict__ out, int n) {
  int i = (blockIdx.x * 256 + threadIdx.x) * 4;
  if (i >= n) return;
  float4 v = *(const float4*)(in + i);
  union { bf16 h[4]; ushort4 u; } r;
  r.h[0] = (bf16)v.x; r.h[1] = (bf16)v.y; r.h[2] = (bf16)v.z; r.h[3] = (bf16)v.w;
  *(ushort4*)(out + i) = r.u;
}

// ---------------- fused weight transposes: all 4 weights in ONE dispatch ----------------
__global__ __launch_bounds__(256) void k_wtrans(const float* __restrict__ w_qkv,
                                                const float* __restrict__ w_proj,
                                                const float* __restrict__ w1,
                                                const float* __restrict__ w2,
                                                bf16* __restrict__ wqkvT,
                                                bf16* __restrict__ wprojT,
                                                bf16* __restrict__ w1T,
                                                bf16* __restrict__ w2T) {
  __shared__ float t[32][33];
  const int bid = blockIdx.x;
  const float* src;
  bf16* dst;
  int K, N, n0, k0;
  if (bid < 768) {            // w_qkv: K=512, N=1536 (48 x 16 tiles)
    src = w_qkv; dst = wqkvT; K = 512; N = 1536;
    n0 = (bid % 48) * 32; k0 = (bid / 48) * 32;
  } else if (bid < 1024) {    // w_proj: 512x512 (16 x 16)
    int i = bid - 768;
    src = w_proj; dst = wprojT; K = 512; N = 512;
    n0 = (i % 16) * 32; k0 = (i / 16) * 32;
  } else if (bid < 2048) {    // w1: K=512, N=2048 (64 x 16)
    int i = bid - 1024;
    src = w1; dst = w1T; K = 512; N = 2048;
    n0 = (i % 64) * 32; k0 = (i / 64) * 32;
  } else {                    // w2: K=2048, N=512 (16 x 64)
    int i = bid - 2048;
    src = w2; dst = w2T; K = 2048; N = 512;
    n0 = (i % 16) * 32; k0 = (i / 16) * 32;
  }
  const int tx = threadIdx.x, ty = threadIdx.y;
#pragma unroll
  for (int j = 0; j < 32; j += 8)
    t[ty + j][tx] = src[(size_t)(k0 + ty + j) * N + n0 + tx];
  __syncthreads();
#pragma unroll
  for (int j = 0; j < 32; j += 8)
    dst[(size_t)(n0 + ty + j) * K + k0 + tx] = (bf16)t[tx][ty + j];
}

// ---------------- GEMM: C[M][N] = A[M][K](bf16) * BT[N][K]^T + bias ----------------
// BM x 128 tile, BK=32, 512 threads = 8 waves (2 wr x 4 wc),
// __launch_bounds__(512,8): VGPR<=64 + 35KB LDS -> 4 blocks/CU = 8 waves/SIMD
// (vs 2 blocks / 4 waves at BK=64). Chunk-rotation swizzle (R12-derived,
// R13-correctness-proven): read chunk = (g + (r16>>1))&3, inverse rotation on
// per-lane global source -> staging writes and b128 frag reads 2-way (free).
// Epilogue bounces C through LDS for coalesced 16-B stores.
template <int BM, bool GELU, bool RESID, bool STORE_BF16>
__global__ __launch_bounds__(512, 8) void k_gemm(const bf16* __restrict__ A,
                                                 const bf16* __restrict__ BT,
                                                 const float* __restrict__ bias,
                                                 const float* __restrict__ resid,
                                                 void* __restrict__ Cout,
                                                 int M, int N, int K) {
  constexpr int MI = BM / 32;          // M-frags per wave (wave M-span = BM/2)
  constexpr size_t MAIN = (size_t)2 * (BM + 128) * 32 * 2;
  constexpr size_t CST = (size_t)BM * 136 * (STORE_BF16 ? 2 : 4);
  constexpr size_t SMEM = MAIN > CST ? MAIN : CST;
  __shared__ __align__(16) char smem[SMEM];
  bf16* Asb = (bf16*)smem;                     // [2][BM*32]
  bf16* Bsb = Asb + 2 * BM * 32;               // [2][128*32]

  const int m0 = blockIdx.y * BM, n0 = blockIdx.x * 128;
  const int tid = threadIdx.x, lane = tid & 63, wid = tid >> 6;
  const int wr = wid >> 2, wc = wid & 3;
  const int r16 = lane & 15, g = lane >> 4;
  const int lrow = lane >> 2;                  // 0..15 rows within a wave's 16-row slab
  const int sc = ((lane & 3) - ((lane >> 3) & 3)) & 3;  // inverse-rotated src chunk

  f32x4 acc[MI][2] = {};

  const int NT = K >> 5;
  auto stage = [&](int t, int buf) {
    const int k0 = t << 5;
    // B: all 8 waves, 16 rows each (128 rows x 64B = 8KB = 512 lanes x 16B)
    {
      int row = wid * 16 + lrow;
      gload16(BT + (size_t)(n0 + row) * K + k0 + sc * 8,
              Bsb + buf * 128 * 32 + (wid * 16) * 32);
    }
    // A: BM/16 wave-slabs (BM=128 -> all 8 waves; BM=64 -> waves 0..3)
    if (BM == 128 || wid < 4) {
      int row = wid * 16 + lrow;
      gload16(A + (size_t)(m0 + row) * K + k0 + sc * 8,
              Asb + buf * BM * 32 + (wid * 16) * 32);
    }
  };

  stage(0, 0);
  __syncthreads();

  for (int t = 0; t < NT; t++) {
    const int cur = t & 1;
    if (t + 1 < NT) stage(t + 1, cur ^ 1);
    const bf16* Ab = Asb + cur * BM * 32;
    const bf16* Bb = Bsb + cur * 128 * 32;
    bf16x8 af[MI], bfr[2];
#pragma unroll
    for (int mi = 0; mi < MI; mi++)
      af[mi] = *(const bf16x8*)(Ab + (wr * (BM / 2) + mi * 16 + r16) * 32 +
                                (((g + (r16 >> 1)) & 3) * 8));
#pragma unroll
    for (int ni = 0; ni < 2; ni++)
      bfr[ni] = *(const bf16x8*)(Bb + (wc * 32 + ni * 16 + r16) * 32 +
                                 (((g + (r16 >> 1)) & 3) * 8));
#pragma unroll
    for (int mi = 0; mi < MI; mi++)
#pragma unroll
      for (int ni = 0; ni < 2; ni++)
        acc[mi][ni] = __builtin_amdgcn_mfma_f32_16x16x32_bf16(af[mi], bfr[ni],
                                                              acc[mi][ni], 0, 0, 0);
    __syncthreads();
  }

  // ---- epilogue: acc -> LDS C-tile -> coalesced 16B stores ----
  float bv[2];
#pragma unroll
  for (int ni = 0; ni < 2; ni++) bv[ni] = bias[n0 + wc * 32 + ni * 16 + r16];

  if (STORE_BF16) {
    bf16* Cl = (bf16*)smem;
#pragma unroll
    for (int mi = 0; mi < MI; mi++)
#pragma unroll
      for (int ni = 0; ni < 2; ni++)
#pragma unroll
        for (int r = 0; r < 4; r++) {
          float v = acc[mi][ni][r] + bv[ni];
          if (GELU) v = 0.5f * v * (1.f + erff(v * 0.70710678118654752f));
          Cl[(wr * (BM / 2) + mi * 16 + 4 * g + r) * 136 + wc * 32 + ni * 16 + r16] =
              (bf16)v;
        }
    __syncthreads();
    constexpr int ROWS_PER = 512 * 8 / 128;  // 32
#pragma unroll
    for (int rr = 0; rr < BM / ROWS_PER; rr++) {
      int row = rr * ROWS_PER + (tid >> 4);
      int cc = (tid & 15) * 8;
      bf16x8 v = *(const bf16x8*)(Cl + row * 136 + cc);
      *(bf16x8*)((bf16*)Cout + (size_t)(m0 + row) * N + n0 + cc) = v;
    }
  } else {
    float* Cl = (float*)smem;
#pragma unroll
    for (int mi = 0; mi < MI; mi++)
#pragma unroll
      for (int ni = 0; ni < 2; ni++)
#pragma unroll
        for (int r = 0; r < 4; r++) {
          float v = acc[mi][ni][r] + bv[ni];
          if (GELU) v = 0.5f * v * (1.f + erff(v * 0.70710678118654752f));
          Cl[(wr * (BM / 2) + mi * 16 + 4 * g + r) * 136 + wc * 32 + ni * 16 + r16] = v;
        }
    __syncthreads();
    constexpr int ROWS_PER = 512 * 4 / 128;  // 16
#pragma unroll
    for (int rr = 0; rr < BM / ROWS_PER; rr++) {
      int row = rr * ROWS_PER + (tid >> 5);
      int cc = (tid & 31) * 4;
      f32x4 v = *(const f32x4*)(Cl + row * 136 + cc);
      if (RESID) {
        f32x4 rv = *(const f32x4*)(resid + (size_t)(m0 + row) * N + n0 + cc);
        v += rv;
      }
      *(f32x4*)((float*)Cout + (size_t)(m0 + row) * N + n0 + cc) = v;
    }
  }
}

// ---------------- V transpose+interleave: qkvb V-cols -> vt[B*H][64][Nq] ----------------
__global__ __launch_bounds__(256) void k_vtrans(const bf16* __restrict__ qkv,
                                                bf16* __restrict__ vt) {
  __shared__ bf16 T[64 * 66];
  const int kvb = blockIdx.x, bh = blockIdx.y;
  const int b = bh >> 3, h = bh & 7;
  const int tid = threadIdx.x, lane = tid & 63, w = tid >> 6;
  const bf16* src = qkv + ((size_t)b * Nq + kvb * 64) * (3 * Dq) + 2 * Dq + h * 64;
#pragma unroll
  for (int i = 0; i < 2; i++) {
    int u = tid + i * 256;
    int r = u >> 3, ch = u & 7;
    *(int4*)(&T[r * 66 + ch * 8]) = *(const int4*)(src + (size_t)r * (3 * Dq) + ch * 8);
  }
  __syncthreads();
  const int kvm = 16 * ((lane >> 2) & 3) + 4 * (lane >> 4) + (lane & 3);
  bf16* dst = vt + (size_t)bh * 64 * Nq + kvb * 64 + lane;
#pragma unroll
  for (int it = 0; it < 16; it++) {
    int e = w * 16 + it;
    dst[(size_t)e * Nq] = T[kvm * 66 + e];
  }
}

// ---------------- flash attention: O^T = V^T P^T, no-max exp2 softmax ----------------
// grid (B*H, Nq/64): 4 waves x 16 q-rows + counted-vmcnt two-barrier schedule.
__global__ __launch_bounds__(256) void k_attn(const bf16* __restrict__ qkv,
                                              const bf16* __restrict__ vt,
                                              bf16* __restrict__ att) {
  __shared__ bf16 Ks[2][64 * 64];
  __shared__ bf16 Vs[2][64 * 64];
  const int qt = blockIdx.y, b = blockIdx.x >> 3, h = blockIdx.x & 7;
  const int tid = threadIdx.x, lane = tid & 63, wid = tid >> 6;
  const int r16 = lane & 15, g = lane >> 4;
  const size_t base = (size_t)b * Nq * (3 * Dq);
  const bf16* qp = qkv + base + h * 64;
  const bf16* kp = qkv + base + Dq + h * 64;
  const bf16* vtp = vt + (size_t)(b * HEADS + h) * 64 * Nq;
  const int q0 = qt * 64 + wid * 16;

  // Q frags, pre-scaled by log2(e) -> S in exp2 domain
  bf16x8 qf[2];
#pragma unroll
  for (int kk = 0; kk < 2; kk++) {
    bf16x8 q = *(const bf16x8*)(qp + (size_t)(q0 + r16) * (3 * Dq) + kk * 32 + g * 8);
#pragma unroll
    for (int j = 0; j < 8; j++) q[j] = (bf16)((float)q[j] * 1.44269504f);
    qf[kk] = q;
  }

  const int srow = lane >> 3;
  const int sch = (lane & 7) ^ srow;
  const bf16x4 ones = {(bf16)1.f, (bf16)1.f, (bf16)1.f, (bf16)1.f};

  f32x4 o[4] = {};
  f32x4 ol = {};              // l accumulator (every row = sum over kv of P)

#pragma unroll
  for (int i = 0; i < 2; i++) {
    int br = (wid * 2 + i) * 8;
    gload16(kp + (size_t)(br + srow) * (3 * Dq) + sch * 8, &Ks[0][br * 64]);
    gload16(vtp + (size_t)(br + srow) * Nq + sch * 8, &Vs[0][br * 64]);
  }
  __syncthreads();  // drains Q loads + stage(0)

  const int NTILES = Nq / 64;
  auto tile = [&](int t, int c) {
    if (t + 1 < NTILES) {
      const int kv1 = (t + 1) * 64;
#pragma unroll
      for (int i = 0; i < 2; i++) {
        int br = (wid * 2 + i) * 8;
        gload16(kp + (size_t)(kv1 + br + srow) * (3 * Dq) + sch * 8,
                &Ks[c ^ 1][br * 64]);
        gload16(vtp + (size_t)(br + srow) * Nq + kv1 + sch * 8, &Vs[c ^ 1][br * 64]);
      }
      VM_BARRIER(4);
    } else {
      VM_BARRIER(0);
    }

    // S^T[kv][q]: s[nt]
    f32x4 s[4] = {};
#pragma unroll
    for (int kk = 0; kk < 2; kk++)
#pragma unroll
      for (int nt = 0; nt < 4; nt++) {
        const bf16x8 kf = *(const bf16x8*)(
            &Ks[c][(nt * 16 + r16) * 64 + (((4 * kk + g) ^ (r16 & 7)) * 8)]);
        s[nt] = __builtin_amdgcn_mfma_f32_16x16x32_bf16(kf, qf[kk], s[nt], 0, 0, 0);
      }

    // no-max softmax: P = 2^s directly (range-safe; O/l cancels the constant)
#pragma unroll
    for (int nt = 0; nt < 4; nt++)
#pragma unroll
      for (int r = 0; r < 4; r++) s[nt][r] = fexp2(s[nt][r]);

    // pack P^T to bf16: pk[s4] IS the 16x16x16 B-frag (k=4g+j, col=r16)
    bf16x4 pk[4];
#pragma unroll
    for (int s4 = 0; s4 < 4; s4++) {
      bf16x4 p;
#pragma unroll
      for (int j = 0; j < 4; j++) p[j] = (bf16)s[s4][j];
      pk[s4] = p;
    }

    // l via MFMA: every row of ol += column-sums of this tile's P
    ol = mfma16(ones, pk[0], ol);
    ol = mfma16(ones, pk[1], ol);
    ol = mfma16(ones, pk[2], ol);
    ol = mfma16(ones, pk[3], ol);

    // PV: O^T[e][q] += V^T A-frags x P^T B-frags, 4 steps of k=16
#pragma unroll
    for (int ot = 0; ot < 4; ot++) {
      const int row = ot * 16 + r16;
      const bf16x8 vf0 = *(const bf16x8*)(
          &Vs[c][row * 64 + (((2 * g + 0) ^ (r16 & 7)) * 8)]);
      const bf16x8 vf1 = *(const bf16x8*)(
          &Vs[c][row * 64 + (((2 * g + 1) ^ (r16 & 7)) * 8)]);
      const bf16x4 a0 = __builtin_shufflevector(vf0, vf0, 0, 1, 2, 3);
      const bf16x4 a1 = __builtin_shufflevector(vf0, vf0, 4, 5, 6, 7);
      const bf16x4 a2 = __builtin_shufflevector(vf1, vf1, 0, 1, 2, 3);
      const bf16x4 a3 = __builtin_shufflevector(vf1, vf1, 4, 5, 6, 7);
      o[ot] = mfma16(a0, pk[0], o[ot]);
      o[ot] = mfma16(a1, pk[1], o[ot]);
      o[ot] = mfma16(a2, pk[2], o[ot]);
      o[ot] = mfma16(a3, pk[3], o[ot]);
    }
    END_BARRIER();
  };

  for (int t = 0; t < NTILES; t += 2) {
    tile(t, 0);
    tile(t + 1, 1);
  }

  asm volatile("s_nop 7\ns_nop 7");  // MFMA->VALU hazard guard before epilogue

  // epilogue: O^T col=q=r16 (same lane as l), row e = ot*16+4g+r
  const float li = 0.125f / ol[0];
  const size_t rowoff = ((size_t)b * Nq + q0 + r16) * Dq + h * 64;
#pragma unroll
  for (int ot = 0; ot < 4; ot++) {
    union { bf16 h[4]; ushort4 u; } r4;
#pragma unroll
    for (int r = 0; r < 4; r++) r4.h[r] = (bf16)(o[ot][r] * li);
    *(ushort4*)(att + rowoff + ot * 16 + 4 * g) = r4.u;
  }
}

// ---------------- LayerNorm over D=512, one wave per row ----------------
template <bool WB>
__global__ __launch_bounds__(64) void k_ln(const float* __restrict__ in,
                                           const float* __restrict__ gamma,
                                           const float* __restrict__ beta,
                                           float* __restrict__ outf,
                                           bf16* __restrict__ outb) {
  const int row = blockIdx.x, lane = threadIdx.x;
  const float* p = in + (size_t)row * Dq + lane * 8;
  float4 a = *(const float4*)p;
  float4 c = *(const float4*)(p + 4);
  float vals[8] = {a.x, a.y, a.z, a.w, c.x, c.y, c.z, c.w};
  float s = 0.f, q = 0.f;
#pragma unroll
  for (int j = 0; j < 8; j++) { s += vals[j]; q += vals[j] * vals[j]; }
#pragma unroll
  for (int off = 1; off < 64; off <<= 1) {
    s += __shfl_xor(s, off);
    q += __shfl_xor(q, off);
  }
  float mean = s * (1.f / Dq);
  float var = q * (1.f / Dq) - mean * mean;
  float rstd = rsqrtf(var + 1e-5f);
  float of[8];
#pragma unroll
  for (int j = 0; j < 8; j++) {
    int col = lane * 8 + j;
    of[j] = (vals[j] - mean) * rstd * gamma[col] + beta[col];
  }
  float4* op = (float4*)(outf + (size_t)row * Dq + lane * 8);
  op[0] = make_float4(of[0], of[1], of[2], of[3]);
  op[1] = make_float4(of[4], of[5], of[6], of[7]);
  if (WB) {
    union { bf16 h[8]; ushort4 u[2]; } rr;
#pragma unroll
    for (int j = 0; j < 8; j++) rr.h[j] = (bf16)of[j];
    ushort4* ob = (ushort4*)(outb + (size_t)row * Dq + lane * 8);
    ob[0] = rr.u[0];
    ob[1] = rr.u[1];
  }
}

extern "C" void kernel_launch(void* const* d_in, const int* in_sizes, int n_in,
                              void* d_out, int out_size, void* d_ws, size_t ws_size,
                              hipStream_t stream) {
  const float* x      = (const float*)d_in[0];
  const float* w_qkv  = (const float*)d_in[1];
  const float* b_qkv  = (const float*)d_in[2];
  const float* w_proj = (const float*)d_in[3];
  const float* b_proj = (const float*)d_in[4];
  const float* ln1_g  = (const float*)d_in[5];
  const float* ln1_b  = (const float*)d_in[6];
  const float* w1     = (const float*)d_in[7];
  const float* b1     = (const float*)d_in[8];
  const float* w2     = (const float*)d_in[9];
  const float* b2     = (const float*)d_in[10];
  const float* ln2_g  = (const float*)d_in[11];
  const float* ln2_b  = (const float*)d_in[12];
  float* out = (float*)d_out;

  const int M = Bq * Nq;  // 8192 rows

  char* p = (char*)d_ws;
  auto alloc = [&](size_t bytes) -> void* {
    char* r = p;
    p += (bytes + 255) & ~(size_t)255;
    return (void*)r;
  };
  bf16* xb     = (bf16*)alloc((size_t)M * Dq * 2);        // x bf16; later reused as att
  bf16* qkvb   = (bf16*)alloc((size_t)M * 3 * Dq * 2);
  bf16* wqkvT  = (bf16*)alloc((size_t)3 * Dq * Dq * 2);
  bf16* wprojT = (bf16*)alloc((size_t)Dq * Dq * 2);
  bf16* w1T    = (bf16*)alloc((size_t)Hq * Dq * 2);
  bf16* w2T    = (bf16*)alloc((size_t)Dq * Hq * 2);
  float* y1    = (float*)alloc((size_t)M * Dq * 4);       // also y2
  float* x1f   = (float*)alloc((size_t)M * Dq * 4);
  bf16* x1b    = (bf16*)alloc((size_t)M * Dq * 2);
  bf16* hb     = (bf16*)alloc((size_t)M * Hq * 2);
  bf16* attb   = xb;   // alias: xb consumed by qkv GEMM before attention writes
  bf16* vtb    = hb;   // alias: hb written by ffn1 only after attention is done

  dim3 tb(32, 8);
  k_cvt_bf16<<<(M * Dq / 4 + 255) / 256, 256, 0, stream>>>(x, xb, M * Dq);
  // all 4 weight transposes fused into one dispatch (3072 tiles)
  k_wtrans<<<3072, tb, 0, stream>>>(w_qkv, w_proj, w1, w2, wqkvT, wprojT, w1T, w2T);

  // qkv = x @ w_qkv + b_qkv
  k_gemm<128, false, false, true><<<dim3((3 * Dq) / 128, M / 128), 512, 0, stream>>>(
      xb, wqkvT, b_qkv, nullptr, qkvb, M, 3 * Dq, Dq);
  // vt = transpose+interleave of V part
  k_vtrans<<<dim3(Nq / 64, Bq * HEADS), 256, 0, stream>>>(qkvb, vtb);
  // attention (QBLK=64: 1024 blocks, 4 blocks/CU)
  k_attn<<<dim3(Bq * HEADS, Nq / 64), 256, 0, stream>>>(qkvb, vtb, attb);
  // y1 = att @ w_proj + b_proj + x
  k_gemm<64, false, true, false><<<dim3(Dq / 128, M / 64), 512, 0, stream>>>(
      attb, wprojT, b_proj, x, y1, M, Dq, Dq);
  // x1 = LN1(y1) -> fp32 + bf16
  k_ln<true><<<M, 64, 0, stream>>>(y1, ln1_g, ln1_b, x1f, x1b);
  // h = gelu(x1 @ w1 + b1)
  k_gemm<128, true, false, true><<<dim3(Hq / 128, M / 128), 512, 0, stream>>>(
      x1b, w1T, b1, nullptr, hb, M, Hq, Dq);
  // y2 = h @ w2 + b2 + x1
  k_gemm<64, false, true, false><<<dim3(Dq / 128, M / 64), 512, 0, stream>>>(
      hb, w2T, b2, x1f, y1, M, Dq, Hq);
  // out = LN2(y2)
  k_ln<false><<<M, 64, 0, stream>>>(y1, ln2_g, ln2_b, out, nullptr);
}

// Round 17
// 174.625 us; speedup vs baseline: 1.0595x; 1.0595x over previous
//
#include <hip/hip_runtime.h>

#define HEADS 8
#define Bq 4
#define Nq 2048
#define Dq 512
#define Hq 2048

typedef __bf16 bf16;
typedef __bf16 bf16x8 __attribute__((ext_vector_type(8)));
typedef __bf16 bf16x4 __attribute__((ext_vector_type(4)));
typedef short short4v __attribute__((ext_vector_type(4)));
typedef float f32x4 __attribute__((ext_vector_type(4)));

__device__ __forceinline__ void gload16(const bf16* g, bf16* s) {
  __builtin_amdgcn_global_load_lds(
      (const __attribute__((address_space(1))) void*)g,
      (__attribute__((address_space(3))) void*)s, 16, 0, 0);
}

__device__ __forceinline__ float fexp2(float x) {
#if __has_builtin(__builtin_amdgcn_exp2f)
  return __builtin_amdgcn_exp2f(x);
#else
  return exp2f(x);
#endif
}

// 16x16x16 bf16 MFMA (legacy shape; A/B = 4 bf16 = 2 VGPR, k = 4g..4g+3 per lane)
__device__ __forceinline__ f32x4 mfma16(bf16x4 a, bf16x4 b, f32x4 c) {
#if __has_builtin(__builtin_amdgcn_mfma_f32_16x16x16bf16_1k)
  return __builtin_amdgcn_mfma_f32_16x16x16bf16_1k(
      __builtin_bit_cast(short4v, a), __builtin_bit_cast(short4v, b), c, 0, 0, 0);
#else
  f32x4 d = c;
  asm("v_mfma_f32_16x16x16_bf16 %0, %1, %2, %0" : "+v"(d) : "v"(a), "v"(b));
  return d;
#endif
}

// counted-vmcnt barrier pair (attn only — helps there, hurts GEMM per R14 A/B)
#define VM_BARRIER(N)                                         \
  do {                                                        \
    asm volatile("s_waitcnt vmcnt(" #N ")" ::: "memory");     \
    __builtin_amdgcn_s_barrier();                             \
    asm volatile("" ::: "memory");                            \
  } while (0)
#define END_BARRIER()                                         \
  do {                                                        \
    asm volatile("" ::: "memory");                            \
    __builtin_amdgcn_s_barrier();                             \
    asm volatile("" ::: "memory");                            \
  } while (0)

// ---------------- fp32 -> bf16 elementwise convert ----------------
__global__ __launch_bounds__(256) void k_cvt_bf16(const float* __restrict__ in,
                                                  bf16* __restrict__ out, int n) {
  int i = (blockIdx.x * 256 + threadIdx.x) * 4;
  if (i >= n) return;
  float4 v = *(const float4*)(in + i);
  union { bf16 h[4]; ushort4 u; } r;
  r.h[0] = (bf16)v.x; r.h[1] = (bf16)v.y; r.h[2] = (bf16)v.z; r.h[3] = (bf16)v.w;
  *(ushort4*)(out + i) = r.u;
}

// ---------------- fused weight transposes: all 4 weights in ONE dispatch ----------------
__global__ __launch_bounds__(256) void k_wtrans(const float* __restrict__ w_qkv,
                                                const float* __restrict__ w_proj,
                                                const float* __restrict__ w1,
                                                const float* __restrict__ w2,
                                                bf16* __restrict__ wqkvT,
                                                bf16* __restrict__ wprojT,
                                                bf16* __restrict__ w1T,
                                                bf16* __restrict__ w2T) {
  __shared__ float t[32][33];
  const int bid = blockIdx.x;
  const float* src;
  bf16* dst;
  int K, N, n0, k0;
  if (bid < 768) {            // w_qkv: K=512, N=1536 (48 x 16 tiles)
    src = w_qkv; dst = wqkvT; K = 512; N = 1536;
    n0 = (bid % 48) * 32; k0 = (bid / 48) * 32;
  } else if (bid < 1024) {    // w_proj: 512x512 (16 x 16)
    int i = bid - 768;
    src = w_proj; dst = wprojT; K = 512; N = 512;
    n0 = (i % 16) * 32; k0 = (i / 16) * 32;
  } else if (bid < 2048) {    // w1: K=512, N=2048 (64 x 16)
    int i = bid - 1024;
    src = w1; dst = w1T; K = 512; N = 2048;
    n0 = (i % 64) * 32; k0 = (i / 64) * 32;
  } else {                    // w2: K=2048, N=512 (16 x 64)
    int i = bid - 2048;
    src = w2; dst = w2T; K = 2048; N = 512;
    n0 = (i % 16) * 32; k0 = (i / 16) * 32;
  }
  const int tx = threadIdx.x, ty = threadIdx.y;
#pragma unroll
  for (int j = 0; j < 32; j += 8)
    t[ty + j][tx] = src[(size_t)(k0 + ty + j) * N + n0 + tx];
  __syncthreads();
#pragma unroll
  for (int j = 0; j < 32; j += 8)
    dst[(size_t)(n0 + ty + j) * K + k0 + tx] = (bf16)t[tx][ty + j];
}

// ---------------- GEMM: C[M][N] = A[M][K](bf16) * BT[N][K]^T + bias ----------------
// R15-best body: BM x 128 tile, BK=64, 512 threads = 8 waves (2 wr x 4 wc),
// global_load_lds width-16 staging, double-buffered, XOR-swizzled b128 frag
// reads, ONE __syncthreads per K-step. NEW: 1D grid + bijective XCD swizzle
// (id&7)*(nwg/8)+(id>>3) with x-fastest logical decode -> all ~GX blocks
// sharing an A-panel land on ONE XCD (panel set fits its 4MB L2, no thrash).
// Epilogue bounces C through LDS for coalesced 16-B stores.
template <int BM, bool GELU, bool RESID, bool STORE_BF16>
__global__ __launch_bounds__(512, 4) void k_gemm(const bf16* __restrict__ A,
                                                 const bf16* __restrict__ BT,
                                                 const float* __restrict__ bias,
                                                 const float* __restrict__ resid,
                                                 void* __restrict__ Cout,
                                                 int M, int N, int K, int GX) {
  constexpr int MI = BM / 32;          // M-frags per wave (wave M-span = BM/2)
  constexpr int AROUNDS = BM / 64;     // 512-thr staging rounds for A
  constexpr size_t MAIN = (size_t)2 * (BM + 128) * 64 * 2;
  constexpr size_t CST = (size_t)BM * 136 * (STORE_BF16 ? 2 : 4);
  constexpr size_t SMEM = MAIN > CST ? MAIN : CST;
  __shared__ __align__(16) char smem[SMEM];
  bf16* Asb = (bf16*)smem;                     // [2][BM*64]
  bf16* Bsb = Asb + 2 * BM * 64;               // [2][128*64]

  // XCD-aware swizzle: dispatch id -> logical id; x fastest so same-A-panel
  // blocks are contiguous and land on one XCD (nwg % 8 == 0 for all shapes).
  const int nwg = gridDim.x;
  const int id = blockIdx.x;
  const int swz = (id & 7) * (nwg >> 3) + (id >> 3);
  const int bx = swz % GX, by = swz / GX;
  const int m0 = by * BM, n0 = bx * 128;

  const int tid = threadIdx.x, lane = tid & 63, wid = tid >> 6;
  const int wr = wid >> 2, wc = wid & 3;
  const int r16 = lane & 15, g = lane >> 4;
  const int lrow = lane >> 3;                  // 0..7 rows within a gload round
  const int sch = (lane & 7) ^ lrow;           // inverse-swizzled source chunk

  f32x4 acc[MI][2] = {};

  const int NT = K >> 6;
  auto stage = [&](int t, int buf) {
    const int k0 = t << 6;
#pragma unroll
    for (int i = 0; i < AROUNDS; i++) {
      int row = i * 64 + wid * 8 + lrow;
      gload16(A + (size_t)(m0 + row) * K + k0 + sch * 8,
              Asb + buf * BM * 64 + (i * 64 + wid * 8) * 64);
    }
#pragma unroll
    for (int i = 0; i < 2; i++) {
      int row = i * 64 + wid * 8 + lrow;
      gload16(BT + (size_t)(n0 + row) * K + k0 + sch * 8,
              Bsb + buf * 128 * 64 + (i * 64 + wid * 8) * 64);
    }
  };

  stage(0, 0);
  __syncthreads();

  for (int t = 0; t < NT; t++) {
    const int cur = t & 1;
    if (t + 1 < NT) stage(t + 1, cur ^ 1);
    const bf16* Ab = Asb + cur * BM * 64;
    const bf16* Bb = Bsb + cur * 128 * 64;
#pragma unroll
    for (int kk = 0; kk < 2; kk++) {
      bf16x8 af[MI], bfr[2];
#pragma unroll
      for (int mi = 0; mi < MI; mi++)
        af[mi] = *(const bf16x8*)(Ab + (wr * (BM / 2) + mi * 16 + r16) * 64 +
                                  (((kk * 4 + g) ^ (r16 & 7)) * 8));
#pragma unroll
      for (int ni = 0; ni < 2; ni++)
        bfr[ni] = *(const bf16x8*)(Bb + (wc * 32 + ni * 16 + r16) * 64 +
                                   (((kk * 4 + g) ^ (r16 & 7)) * 8));
#pragma unroll
      for (int mi = 0; mi < MI; mi++)
#pragma unroll
        for (int ni = 0; ni < 2; ni++)
          acc[mi][ni] = __builtin_amdgcn_mfma_f32_16x16x32_bf16(af[mi], bfr[ni],
                                                                acc[mi][ni], 0, 0, 0);
    }
    __syncthreads();
  }

  // ---- epilogue: acc -> LDS C-tile -> coalesced 16B stores ----
  float bv[2];
#pragma unroll
  for (int ni = 0; ni < 2; ni++) bv[ni] = bias[n0 + wc * 32 + ni * 16 + r16];

  if (STORE_BF16) {
    bf16* Cl = (bf16*)smem;
#pragma unroll
    for (int mi = 0; mi < MI; mi++)
#pragma unroll
      for (int ni = 0; ni < 2; ni++)
#pragma unroll
        for (int r = 0; r < 4; r++) {
          float v = acc[mi][ni][r] + bv[ni];
          if (GELU) v = 0.5f * v * (1.f + erff(v * 0.70710678118654752f));
          Cl[(wr * (BM / 2) + mi * 16 + 4 * g + r) * 136 + wc * 32 + ni * 16 + r16] =
              (bf16)v;
        }
    __syncthreads();
    constexpr int ROWS_PER = 512 * 8 / 128;  // 32
#pragma unroll
    for (int rr = 0; rr < BM / ROWS_PER; rr++) {
      int row = rr * ROWS_PER + (tid >> 4);
      int cc = (tid & 15) * 8;
      bf16x8 v = *(const bf16x8*)(Cl + row * 136 + cc);
      *(bf16x8*)((bf16*)Cout + (size_t)(m0 + row) * N + n0 + cc) = v;
    }
  } else {
    float* Cl = (float*)smem;
#pragma unroll
    for (int mi = 0; mi < MI; mi++)
#pragma unroll
      for (int ni = 0; ni < 2; ni++)
#pragma unroll
        for (int r = 0; r < 4; r++) {
          float v = acc[mi][ni][r] + bv[ni];
          if (GELU) v = 0.5f * v * (1.f + erff(v * 0.70710678118654752f));
          Cl[(wr * (BM / 2) + mi * 16 + 4 * g + r) * 136 + wc * 32 + ni * 16 + r16] = v;
        }
    __syncthreads();
    constexpr int ROWS_PER = 512 * 4 / 128;  // 16
#pragma unroll
    for (int rr = 0; rr < BM / ROWS_PER; rr++) {
      int row = rr * ROWS_PER + (tid >> 5);
      int cc = (tid & 31) * 4;
      f32x4 v = *(const f32x4*)(Cl + row * 136 + cc);
      if (RESID) {
        f32x4 rv = *(const f32x4*)(resid + (size_t)(m0 + row) * N + n0 + cc);
        v += rv;
      }
      *(f32x4*)((float*)Cout + (size_t)(m0 + row) * N + n0 + cc) = v;
    }
  }
}

// ---------------- V transpose+interleave: qkvb V-cols -> vt[B*H][64][Nq] ----------------
__global__ __launch_bounds__(256) void k_vtrans(const bf16* __restrict__ qkv,
                                                bf16* __restrict__ vt) {
  __shared__ bf16 T[64 * 66];
  const int kvb = blockIdx.x, bh = blockIdx.y;
  const int b = bh >> 3, h = bh & 7;
  const int tid = threadIdx.x, lane = tid & 63, w = tid >> 6;
  const bf16* src = qkv + ((size_t)b * Nq + kvb * 64) * (3 * Dq) + 2 * Dq + h * 64;
#pragma unroll
  for (int i = 0; i < 2; i++) {
    int u = tid + i * 256;
    int r = u >> 3, ch = u & 7;
    *(int4*)(&T[r * 66 + ch * 8]) = *(const int4*)(src + (size_t)r * (3 * Dq) + ch * 8);
  }
  __syncthreads();
  const int kvm = 16 * ((lane >> 2) & 3) + 4 * (lane >> 4) + (lane & 3);
  bf16* dst = vt + (size_t)bh * 64 * Nq + kvb * 64 + lane;
#pragma unroll
  for (int it = 0; it < 16; it++) {
    int e = w * 16 + it;
    dst[(size_t)e * Nq] = T[kvm * 66 + e];
  }
}

// ---------------- flash attention: O^T = V^T P^T, no-max exp2 softmax ----------------
// grid (B*H, Nq/64): 4 waves x 16 q-rows + counted-vmcnt two-barrier schedule.
__global__ __launch_bounds__(256) void k_attn(const bf16* __restrict__ qkv,
                                              const bf16* __restrict__ vt,
                                              bf16* __restrict__ att) {
  __shared__ bf16 Ks[2][64 * 64];
  __shared__ bf16 Vs[2][64 * 64];
  const int qt = blockIdx.y, b = blockIdx.x >> 3, h = blockIdx.x & 7;
  const int tid = threadIdx.x, lane = tid & 63, wid = tid >> 6;
  const int r16 = lane & 15, g = lane >> 4;
  const size_t base = (size_t)b * Nq * (3 * Dq);
  const bf16* qp = qkv + base + h * 64;
  const bf16* kp = qkv + base + Dq + h * 64;
  const bf16* vtp = vt + (size_t)(b * HEADS + h) * 64 * Nq;
  const int q0 = qt * 64 + wid * 16;

  // Q frags, pre-scaled by log2(e) -> S in exp2 domain
  bf16x8 qf[2];
#pragma unroll
  for (int kk = 0; kk < 2; kk++) {
    bf16x8 q = *(const bf16x8*)(qp + (size_t)(q0 + r16) * (3 * Dq) + kk * 32 + g * 8);
#pragma unroll
    for (int j = 0; j < 8; j++) q[j] = (bf16)((float)q[j] * 1.44269504f);
    qf[kk] = q;
  }

  const int srow = lane >> 3;
  const int sch = (lane & 7) ^ srow;
  const bf16x4 ones = {(bf16)1.f, (bf16)1.f, (bf16)1.f, (bf16)1.f};

  f32x4 o[4] = {};
  f32x4 ol = {};              // l accumulator (every row = sum over kv of P)

#pragma unroll
  for (int i = 0; i < 2; i++) {
    int br = (wid * 2 + i) * 8;
    gload16(kp + (size_t)(br + srow) * (3 * Dq) + sch * 8, &Ks[0][br * 64]);
    gload16(vtp + (size_t)(br + srow) * Nq + sch * 8, &Vs[0][br * 64]);
  }
  __syncthreads();  // drains Q loads + stage(0)

  const int NTILES = Nq / 64;
  auto tile = [&](int t, int c) {
    if (t + 1 < NTILES) {
      const int kv1 = (t + 1) * 64;
#pragma unroll
      for (int i = 0; i < 2; i++) {
        int br = (wid * 2 + i) * 8;
        gload16(kp + (size_t)(kv1 + br + srow) * (3 * Dq) + sch * 8,
                &Ks[c ^ 1][br * 64]);
        gload16(vtp + (size_t)(br + srow) * Nq + kv1 + sch * 8, &Vs[c ^ 1][br * 64]);
      }
      VM_BARRIER(4);
    } else {
      VM_BARRIER(0);
    }

    // S^T[kv][q]: s[nt]
    f32x4 s[4] = {};
#pragma unroll
    for (int kk = 0; kk < 2; kk++)
#pragma unroll
      for (int nt = 0; nt < 4; nt++) {
        const bf16x8 kf = *(const bf16x8*)(
            &Ks[c][(nt * 16 + r16) * 64 + (((4 * kk + g) ^ (r16 & 7)) * 8)]);
        s[nt] = __builtin_amdgcn_mfma_f32_16x16x32_bf16(kf, qf[kk], s[nt], 0, 0, 0);
      }

    // no-max softmax: P = 2^s directly (range-safe; O/l cancels the constant)
#pragma unroll
    for (int nt = 0; nt < 4; nt++)
#pragma unroll
      for (int r = 0; r < 4; r++) s[nt][r] = fexp2(s[nt][r]);

    // pack P^T to bf16: pk[s4] IS the 16x16x16 B-frag (k=4g+j, col=r16)
    bf16x4 pk[4];
#pragma unroll
    for (int s4 = 0; s4 < 4; s4++) {
      bf16x4 p;
#pragma unroll
      for (int j = 0; j < 4; j++) p[j] = (bf16)s[s4][j];
      pk[s4] = p;
    }

    // l via MFMA: every row of ol += column-sums of this tile's P
    ol = mfma16(ones, pk[0], ol);
    ol = mfma16(ones, pk[1], ol);
    ol = mfma16(ones, pk[2], ol);
    ol = mfma16(ones, pk[3], ol);

    // PV: O^T[e][q] += V^T A-frags x P^T B-frags, 4 steps of k=16
#pragma unroll
    for (int ot = 0; ot < 4; ot++) {
      const int row = ot * 16 + r16;
      const bf16x8 vf0 = *(const bf16x8*)(
          &Vs[c][row * 64 + (((2 * g + 0) ^ (r16 & 7)) * 8)]);
      const bf16x8 vf1 = *(const bf16x8*)(
          &Vs[c][row * 64 + (((2 * g + 1) ^ (r16 & 7)) * 8)]);
      const bf16x4 a0 = __builtin_shufflevector(vf0, vf0, 0, 1, 2, 3);
      const bf16x4 a1 = __builtin_shufflevector(vf0, vf0, 4, 5, 6, 7);
      const bf16x4 a2 = __builtin_shufflevector(vf1, vf1, 0, 1, 2, 3);
      const bf16x4 a3 = __builtin_shufflevector(vf1, vf1, 4, 5, 6, 7);
      o[ot] = mfma16(a0, pk[0], o[ot]);
      o[ot] = mfma16(a1, pk[1], o[ot]);
      o[ot] = mfma16(a2, pk[2], o[ot]);
      o[ot] = mfma16(a3, pk[3], o[ot]);
    }
    END_BARRIER();
  };

  for (int t = 0; t < NTILES; t += 2) {
    tile(t, 0);
    tile(t + 1, 1);
  }

  asm volatile("s_nop 7\ns_nop 7");  // MFMA->VALU hazard guard before epilogue

  // epilogue: O^T col=q=r16 (same lane as l), row e = ot*16+4g+r
  const float li = 0.125f / ol[0];
  const size_t rowoff = ((size_t)b * Nq + q0 + r16) * Dq + h * 64;
#pragma unroll
  for (int ot = 0; ot < 4; ot++) {
    union { bf16 h[4]; ushort4 u; } r4;
#pragma unroll
    for (int r = 0; r < 4; r++) r4.h[r] = (bf16)(o[ot][r] * li);
    *(ushort4*)(att + rowoff + ot * 16 + 4 * g) = r4.u;
  }
}

// ---------------- LayerNorm over D=512: 4 rows per 256-thr block ----------------
template <bool WB>
__global__ __launch_bounds__(256) void k_ln(const float* __restrict__ in,
                                            const float* __restrict__ gamma,
                                            const float* __restrict__ beta,
                                            float* __restrict__ outf,
                                            bf16* __restrict__ outb) {
  const int row = blockIdx.x * 4 + threadIdx.y;
  const int lane = threadIdx.x;
  const float* p = in + (size_t)row * Dq + lane * 8;
  float4 a = *(const float4*)p;
  float4 c = *(const float4*)(p + 4);
  float vals[8] = {a.x, a.y, a.z, a.w, c.x, c.y, c.z, c.w};
  float s = 0.f, q = 0.f;
#pragma unroll
  for (int j = 0; j < 8; j++) { s += vals[j]; q += vals[j] * vals[j]; }
#pragma unroll
  for (int off = 1; off < 64; off <<= 1) {
    s += __shfl_xor(s, off);
    q += __shfl_xor(q, off);
  }
  float mean = s * (1.f / Dq);
  float var = q * (1.f / Dq) - mean * mean;
  float rstd = rsqrtf(var + 1e-5f);
  float of[8];
#pragma unroll
  for (int j = 0; j < 8; j++) {
    int col = lane * 8 + j;
    of[j] = (vals[j] - mean) * rstd * gamma[col] + beta[col];
  }
  float4* op = (float4*)(outf + (size_t)row * Dq + lane * 8);
  op[0] = make_float4(of[0], of[1], of[2], of[3]);
  op[1] = make_float4(of[4], of[5], of[6], of[7]);
  if (WB) {
    union { bf16 h[8]; ushort4 u[2]; } rr;
#pragma unroll
    for (int j = 0; j < 8; j++) rr.h[j] = (bf16)of[j];
    ushort4* ob = (ushort4*)(outb + (size_t)row * Dq + lane * 8);
    ob[0] = rr.u[0];
    ob[1] = rr.u[1];
  }
}

extern "C" void kernel_launch(void* const* d_in, const int* in_sizes, int n_in,
                              void* d_out, int out_size, void* d_ws, size_t ws_size,
                              hipStream_t stream) {
  const float* x      = (const float*)d_in[0];
  const float* w_qkv  = (const float*)d_in[1];
  const float* b_qkv  = (const float*)d_in[2];
  const float* w_proj = (const float*)d_in[3];
  const float* b_proj = (const float*)d_in[4];
  const float* ln1_g  = (const float*)d_in[5];
  const float* ln1_b  = (const float*)d_in[6];
  const float* w1     = (const float*)d_in[7];
  const float* b1     = (const float*)d_in[8];
  const float* w2     = (const float*)d_in[9];
  const float* b2     = (const float*)d_in[10];
  const float* ln2_g  = (const float*)d_in[11];
  const float* ln2_b  = (const float*)d_in[12];
  float* out = (float*)d_out;

  const int M = Bq * Nq;  // 8192 rows

  char* p = (char*)d_ws;
  auto alloc = [&](size_t bytes) -> void* {
    char* r = p;
    p += (bytes + 255) & ~(size_t)255;
    return (void*)r;
  };
  bf16* xb     = (bf16*)alloc((size_t)M * Dq * 2);        // x bf16; later reused as att
  bf16* qkvb   = (bf16*)alloc((size_t)M * 3 * Dq * 2);
  bf16* wqkvT  = (bf16*)alloc((size_t)3 * Dq * Dq * 2);
  bf16* wprojT = (bf16*)alloc((size_t)Dq * Dq * 2);
  bf16* w1T    = (bf16*)alloc((size_t)Hq * Dq * 2);
  bf16* w2T    = (bf16*)alloc((size_t)Dq * Hq * 2);
  float* y1    = (float*)alloc((size_t)M * Dq * 4);       // also y2
  float* x1f   = (float*)alloc((size_t)M * Dq * 4);
  bf16* x1b    = (bf16*)alloc((size_t)M * Dq * 2);
  bf16* hb     = (bf16*)alloc((size_t)M * Hq * 2);
  bf16* attb   = xb;   // alias: xb consumed by qkv GEMM before attention writes
  bf16* vtb    = hb;   // alias: hb written by ffn1 only after attention is done

  dim3 tb(32, 8);
  k_cvt_bf16<<<(M * Dq / 4 + 255) / 256, 256, 0, stream>>>(x, xb, M * Dq);
  // all 4 weight transposes fused into one dispatch (3072 tiles)
  k_wtrans<<<3072, tb, 0, stream>>>(w_qkv, w_proj, w1, w2, wqkvT, wprojT, w1T, w2T);

  // qkv = x @ w_qkv + b_qkv   (1D grid, XCD-swizzled: GX=12, nwg=768)
  k_gemm<128, false, false, true><<<768, 512, 0, stream>>>(
      xb, wqkvT, b_qkv, nullptr, qkvb, M, 3 * Dq, Dq, 12);
  // vt = transpose+interleave of V part
  k_vtrans<<<dim3(Nq / 64, Bq * HEADS), 256, 0, stream>>>(qkvb, vtb);
  // attention (QBLK=64: 1024 blocks, 4 blocks/CU)
  k_attn<<<dim3(Bq * HEADS, Nq / 64), 256, 0, stream>>>(qkvb, vtb, attb);
  // y1 = att @ w_proj + b_proj + x   (GX=4, nwg=512)
  k_gemm<64, false, true, false><<<512, 512, 0, stream>>>(
      attb, wprojT, b_proj, x, y1, M, Dq, Dq, 4);
  // x1 = LN1(y1) -> fp32 + bf16   (4 rows/block)
  k_ln<true><<<M / 4, dim3(64, 4), 0, stream>>>(y1, ln1_g, ln1_b, x1f, x1b);
  // h = gelu(x1 @ w1 + b1)   (GX=16, nwg=1024)
  k_gemm<128, true, false, true><<<1024, 512, 0, stream>>>(
      x1b, w1T, b1, nullptr, hb, M, Hq, Dq, 16);
  // y2 = h @ w2 + b2 + x1   (GX=4, nwg=512)
  k_gemm<64, false, true, false><<<512, 512, 0, stream>>>(
      hb, w2T, b2, x1f, y1, M, Dq, Hq, 4);
  // out = LN2(y2)
  k_ln<false><<<M / 4, dim3(64, 4), 0, stream>>>(y1, ln2_g, ln2_b, out, nullptr);
}

// Round 18
// 169.030 us; speedup vs baseline: 1.0945x; 1.0331x over previous
//
#include <hip/hip_runtime.h>

#define HEADS 8
#define Bq 4
#define Nq 2048
#define Dq 512
#define Hq 2048

typedef __bf16 bf16;
typedef __bf16 bf16x8 __attribute__((ext_vector_type(8)));
typedef __bf16 bf16x4 __attribute__((ext_vector_type(4)));
typedef short short4v __attribute__((ext_vector_type(4)));
typedef float f32x4 __attribute__((ext_vector_type(4)));

__device__ __forceinline__ void gload16(const bf16* g, bf16* s) {
  __builtin_amdgcn_global_load_lds(
      (const __attribute__((address_space(1))) void*)g,
      (__attribute__((address_space(3))) void*)s, 16, 0, 0);
}

__device__ __forceinline__ float fexp2(float x) {
#if __has_builtin(__builtin_amdgcn_exp2f)
  return __builtin_amdgcn_exp2f(x);
#else
  return exp2f(x);
#endif
}

// counted-vmcnt barrier pair (attn only — helps there, hurts GEMM per R14 A/B)
#define VM_BARRIER(N)                                         \
  do {                                                        \
    asm volatile("s_waitcnt vmcnt(" #N ")" ::: "memory");     \
    __builtin_amdgcn_s_barrier();                             \
    asm volatile("" ::: "memory");                            \
  } while (0)
#define END_BARRIER()                                         \
  do {                                                        \
    asm volatile("" ::: "memory");                            \
    __builtin_amdgcn_s_barrier();                             \
    asm volatile("" ::: "memory");                            \
  } while (0)

// ---------------- fp32 -> bf16 elementwise convert ----------------
__global__ __launch_bounds__(256) void k_cvt_bf16(const float* __restrict__ in,
                                                  bf16* __restrict__ out, int n) {
  int i = (blockIdx.x * 256 + threadIdx.x) * 4;
  if (i >= n) return;
  float4 v = *(const float4*)(in + i);
  union { bf16 h[4]; ushort4 u; } r;
  r.h[0] = (bf16)v.x; r.h[1] = (bf16)v.y; r.h[2] = (bf16)v.z; r.h[3] = (bf16)v.w;
  *(ushort4*)(out + i) = r.u;
}

// ---------------- fused weight transposes: all 4 weights in ONE dispatch ----------------
__global__ __launch_bounds__(256) void k_wtrans(const float* __restrict__ w_qkv,
                                                const float* __restrict__ w_proj,
                                                const float* __restrict__ w1,
                                                const float* __restrict__ w2,
                                                bf16* __restrict__ wqkvT,
                                                bf16* __restrict__ wprojT,
                                                bf16* __restrict__ w1T,
                                                bf16* __restrict__ w2T) {
  __shared__ float t[32][33];
  const int bid = blockIdx.x;
  const float* src;
  bf16* dst;
  int K, N, n0, k0;
  if (bid < 768) {            // w_qkv: K=512, N=1536 (48 x 16 tiles)
    src = w_qkv; dst = wqkvT; K = 512; N = 1536;
    n0 = (bid % 48) * 32; k0 = (bid / 48) * 32;
  } else if (bid < 1024) {    // w_proj: 512x512 (16 x 16)
    int i = bid - 768;
    src = w_proj; dst = wprojT; K = 512; N = 512;
    n0 = (i % 16) * 32; k0 = (i / 16) * 32;
  } else if (bid < 2048) {    // w1: K=512, N=2048 (64 x 16)
    int i = bid - 1024;
    src = w1; dst = w1T; K = 512; N = 2048;
    n0 = (i % 64) * 32; k0 = (i / 64) * 32;
  } else {                    // w2: K=2048, N=512 (16 x 64)
    int i = bid - 2048;
    src = w2; dst = w2T; K = 2048; N = 512;
    n0 = (i % 16) * 32; k0 = (i / 16) * 32;
  }
  const int tx = threadIdx.x, ty = threadIdx.y;
#pragma unroll
  for (int j = 0; j < 32; j += 8)
    t[ty + j][tx] = src[(size_t)(k0 + ty + j) * N + n0 + tx];
  __syncthreads();
#pragma unroll
  for (int j = 0; j < 32; j += 8)
    dst[(size_t)(n0 + ty + j) * K + k0 + tx] = (bf16)t[tx][ty + j];
}

// ---------------- GEMM: C[M][N] = A[M][K](bf16) * BT[N][K]^T + bias ----------------
// R15-best body + XCD swizzle (R17): BM x 128 tile, BK=64, 512 threads = 8
// waves, global_load_lds staging, double-buffered, XOR-swizzled b128 frag
// reads, ONE __syncthreads per K-step. Epilogue bounces C through LDS.
template <int BM, bool GELU, bool RESID, bool STORE_BF16>
__global__ __launch_bounds__(512, 4) void k_gemm(const bf16* __restrict__ A,
                                                 const bf16* __restrict__ BT,
                                                 const float* __restrict__ bias,
                                                 const float* __restrict__ resid,
                                                 void* __restrict__ Cout,
                                                 int M, int N, int K, int GX) {
  constexpr int MI = BM / 32;
  constexpr int AROUNDS = BM / 64;
  constexpr size_t MAIN = (size_t)2 * (BM + 128) * 64 * 2;
  constexpr size_t CST = (size_t)BM * 136 * (STORE_BF16 ? 2 : 4);
  constexpr size_t SMEM = MAIN > CST ? MAIN : CST;
  __shared__ __align__(16) char smem[SMEM];
  bf16* Asb = (bf16*)smem;
  bf16* Bsb = Asb + 2 * BM * 64;

  const int nwg = gridDim.x;
  const int id = blockIdx.x;
  const int swz = (id & 7) * (nwg >> 3) + (id >> 3);
  const int bx = swz % GX, by = swz / GX;
  const int m0 = by * BM, n0 = bx * 128;

  const int tid = threadIdx.x, lane = tid & 63, wid = tid >> 6;
  const int wr = wid >> 2, wc = wid & 3;
  const int r16 = lane & 15, g = lane >> 4;
  const int lrow = lane >> 3;
  const int sch = (lane & 7) ^ lrow;

  f32x4 acc[MI][2] = {};

  const int NT = K >> 6;
  auto stage = [&](int t, int buf) {
    const int k0 = t << 6;
#pragma unroll
    for (int i = 0; i < AROUNDS; i++) {
      int row = i * 64 + wid * 8 + lrow;
      gload16(A + (size_t)(m0 + row) * K + k0 + sch * 8,
              Asb + buf * BM * 64 + (i * 64 + wid * 8) * 64);
    }
#pragma unroll
    for (int i = 0; i < 2; i++) {
      int row = i * 64 + wid * 8 + lrow;
      gload16(BT + (size_t)(n0 + row) * K + k0 + sch * 8,
              Bsb + buf * 128 * 64 + (i * 64 + wid * 8) * 64);
    }
  };

  stage(0, 0);
  __syncthreads();

  for (int t = 0; t < NT; t++) {
    const int cur = t & 1;
    if (t + 1 < NT) stage(t + 1, cur ^ 1);
    const bf16* Ab = Asb + cur * BM * 64;
    const bf16* Bb = Bsb + cur * 128 * 64;
#pragma unroll
    for (int kk = 0; kk < 2; kk++) {
      bf16x8 af[MI], bfr[2];
#pragma unroll
      for (int mi = 0; mi < MI; mi++)
        af[mi] = *(const bf16x8*)(Ab + (wr * (BM / 2) + mi * 16 + r16) * 64 +
                                  (((kk * 4 + g) ^ (r16 & 7)) * 8));
#pragma unroll
      for (int ni = 0; ni < 2; ni++)
        bfr[ni] = *(const bf16x8*)(Bb + (wc * 32 + ni * 16 + r16) * 64 +
                                   (((kk * 4 + g) ^ (r16 & 7)) * 8));
#pragma unroll
      for (int mi = 0; mi < MI; mi++)
#pragma unroll
        for (int ni = 0; ni < 2; ni++)
          acc[mi][ni] = __builtin_amdgcn_mfma_f32_16x16x32_bf16(af[mi], bfr[ni],
                                                                acc[mi][ni], 0, 0, 0);
    }
    __syncthreads();
  }

  float bv[2];
#pragma unroll
  for (int ni = 0; ni < 2; ni++) bv[ni] = bias[n0 + wc * 32 + ni * 16 + r16];

  if (STORE_BF16) {
    bf16* Cl = (bf16*)smem;
#pragma unroll
    for (int mi = 0; mi < MI; mi++)
#pragma unroll
      for (int ni = 0; ni < 2; ni++)
#pragma unroll
        for (int r = 0; r < 4; r++) {
          float v = acc[mi][ni][r] + bv[ni];
          if (GELU) v = 0.5f * v * (1.f + erff(v * 0.70710678118654752f));
          Cl[(wr * (BM / 2) + mi * 16 + 4 * g + r) * 136 + wc * 32 + ni * 16 + r16] =
              (bf16)v;
        }
    __syncthreads();
    constexpr int ROWS_PER = 512 * 8 / 128;  // 32
#pragma unroll
    for (int rr = 0; rr < BM / ROWS_PER; rr++) {
      int row = rr * ROWS_PER + (tid >> 4);
      int cc = (tid & 15) * 8;
      bf16x8 v = *(const bf16x8*)(Cl + row * 136 + cc);
      *(bf16x8*)((bf16*)Cout + (size_t)(m0 + row) * N + n0 + cc) = v;
    }
  } else {
    float* Cl = (float*)smem;
#pragma unroll
    for (int mi = 0; mi < MI; mi++)
#pragma unroll
      for (int ni = 0; ni < 2; ni++)
#pragma unroll
        for (int r = 0; r < 4; r++) {
          float v = acc[mi][ni][r] + bv[ni];
          if (GELU) v = 0.5f * v * (1.f + erff(v * 0.70710678118654752f));
          Cl[(wr * (BM / 2) + mi * 16 + 4 * g + r) * 136 + wc * 32 + ni * 16 + r16] = v;
        }
    __syncthreads();
    constexpr int ROWS_PER = 512 * 4 / 128;  // 16
#pragma unroll
    for (int rr = 0; rr < BM / ROWS_PER; rr++) {
      int row = rr * ROWS_PER + (tid >> 5);
      int cc = (tid & 31) * 4;
      f32x4 v = *(const f32x4*)(Cl + row * 136 + cc);
      if (RESID) {
        f32x4 rv = *(const f32x4*)(resid + (size_t)(m0 + row) * N + n0 + cc);
        v += rv;
      }
      *(f32x4*)((float*)Cout + (size_t)(m0 + row) * N + n0 + cc) = v;
    }
  }
}

// ---------------- V transpose (plain): qkvb V-cols -> vt[B*H][64][Nq] ----------------
// No interleave needed anymore: with K-row-permuted QK^T, P's B-frag k-order is
// linear kv, so V^T is consumed in natural order.
__global__ __launch_bounds__(256) void k_vtrans(const bf16* __restrict__ qkv,
                                                bf16* __restrict__ vt) {
  __shared__ bf16 T[64 * 66];
  const int kvb = blockIdx.x, bh = blockIdx.y;
  const int b = bh >> 3, h = bh & 7;
  const int tid = threadIdx.x, lane = tid & 63, w = tid >> 6;
  const bf16* src = qkv + ((size_t)b * Nq + kvb * 64) * (3 * Dq) + 2 * Dq + h * 64;
#pragma unroll
  for (int i = 0; i < 2; i++) {
    int u = tid + i * 256;
    int r = u >> 3, ch = u & 7;
    *(int4*)(&T[r * 66 + ch * 8]) = *(const int4*)(src + (size_t)r * (3 * Dq) + ch * 8);
  }
  __syncthreads();
  bf16* dst = vt + (size_t)bh * 64 * Nq + kvb * 64 + lane;
#pragma unroll
  for (int it = 0; it < 16; it++) {
    int e = w * 16 + it;
    dst[(size_t)e * Nq] = T[lane * 66 + e];
  }
}

// ---------------- flash attention: all-K=32 MFMA, no-max exp2 softmax ----------------
// grid (B*H, Nq/64): 4 waves x 16 q-rows, counted-vmcnt schedule.
// K staged with row permutation f(nt,i)=32(nt>>1)+8(i>>2)+4(nt&1)+(i&3) via
// per-lane gload SOURCE address (dest linear). Then lane g's packed P across
// tile pair (2kk,2kk+1) = kv 32kk+8g..+7 = native mfma_16x16x32 B-frag ->
// PV = 8 mfma32 (was 16 mfma16), l = 2 (was 4); V^T consumed linearly.
__global__ __launch_bounds__(256) void k_attn(const bf16* __restrict__ qkv,
                                              const bf16* __restrict__ vt,
                                              bf16* __restrict__ att) {
  __shared__ bf16 Ks[2][64 * 64];
  __shared__ bf16 Vs[2][64 * 64];
  const int qt = blockIdx.y, b = blockIdx.x >> 3, h = blockIdx.x & 7;
  const int tid = threadIdx.x, lane = tid & 63, wid = tid >> 6;
  const int r16 = lane & 15, g = lane >> 4;
  const size_t base = (size_t)b * Nq * (3 * Dq);
  const bf16* qp = qkv + base + h * 64;
  const bf16* kp = qkv + base + Dq + h * 64;
  const bf16* vtp = vt + (size_t)(b * HEADS + h) * 64 * Nq;
  const int q0 = qt * 64 + wid * 16;

  // Q frags, pre-scaled by log2(e) -> S in exp2 domain
  bf16x8 qf[2];
#pragma unroll
  for (int kk = 0; kk < 2; kk++) {
    bf16x8 q = *(const bf16x8*)(qp + (size_t)(q0 + r16) * (3 * Dq) + kk * 32 + g * 8);
#pragma unroll
    for (int j = 0; j < 8; j++) q[j] = (bf16)((float)q[j] * 1.44269504f);
    qf[kk] = q;
  }

  const int srow = lane >> 3;
  const int sch = (lane & 7) ^ srow;
  // per-lane permuted source rows for K staging (d = dest row within 64-tile)
  int fsrc[2];
#pragma unroll
  for (int i = 0; i < 2; i++) {
    int d = (wid * 2 + i) * 8 + srow;
    fsrc[i] = ((d >> 5) << 5) + 8 * ((d & 15) >> 2) + 4 * ((d >> 4) & 1) + (d & 3);
  }

  bf16x8 ones8;
#pragma unroll
  for (int j = 0; j < 8; j++) ones8[j] = (bf16)1.f;

  f32x4 o[4] = {};
  f32x4 ol = {};              // l accumulator (every row = sum over kv of P)

#pragma unroll
  for (int i = 0; i < 2; i++) {
    int br = (wid * 2 + i) * 8;
    gload16(kp + (size_t)fsrc[i] * (3 * Dq) + sch * 8, &Ks[0][br * 64]);
    gload16(vtp + (size_t)(br + srow) * Nq + sch * 8, &Vs[0][br * 64]);
  }
  __syncthreads();  // drains Q loads + stage(0)

  const int NTILES = Nq / 64;
  auto tile = [&](int t, int c) {
    if (t + 1 < NTILES) {
      const int kv1 = (t + 1) * 64;
#pragma unroll
      for (int i = 0; i < 2; i++) {
        int br = (wid * 2 + i) * 8;
        gload16(kp + (size_t)(kv1 + fsrc[i]) * (3 * Dq) + sch * 8,
                &Ks[c ^ 1][br * 64]);
        gload16(vtp + (size_t)(br + srow) * Nq + kv1 + sch * 8, &Vs[c ^ 1][br * 64]);
      }
      VM_BARRIER(4);
    } else {
      VM_BARRIER(0);
    }

    // S^T[kv'][q], kv' permuted: lane(g,r) of tile nt holds kv = f(nt,4g+r)
    f32x4 s[4] = {};
#pragma unroll
    for (int kk = 0; kk < 2; kk++)
#pragma unroll
      for (int nt = 0; nt < 4; nt++) {
        const bf16x8 kf = *(const bf16x8*)(
            &Ks[c][(nt * 16 + r16) * 64 + (((4 * kk + g) ^ (r16 & 7)) * 8)]);
        s[nt] = __builtin_amdgcn_mfma_f32_16x16x32_bf16(kf, qf[kk], s[nt], 0, 0, 0);
      }

    // no-max softmax: P = 2^s directly (range-safe; O/l cancels the constant)
#pragma unroll
    for (int nt = 0; nt < 4; nt++)
#pragma unroll
      for (int r = 0; r < 4; r++) s[nt][r] = fexp2(s[nt][r]);

    // pack to native K=32 B-frags: pb[kk][j] = P[kv=32kk+8g+j][q=r16]
    bf16x8 pb[2];
#pragma unroll
    for (int kk = 0; kk < 2; kk++) {
      bf16x8 t8;
#pragma unroll
      for (int r = 0; r < 4; r++) {
        t8[r] = (bf16)s[2 * kk][r];
        t8[4 + r] = (bf16)s[2 * kk + 1][r];
      }
      pb[kk] = t8;
    }

    // l via MFMA (K=32): every row of ol += column-sums of P
    ol = __builtin_amdgcn_mfma_f32_16x16x32_bf16(ones8, pb[0], ol, 0, 0, 0);
    ol = __builtin_amdgcn_mfma_f32_16x16x32_bf16(ones8, pb[1], ol, 0, 0, 0);

    // PV: O^T[e][q] += V^T A-frags (k=8g+j linear kv) x P B-frags, K=32 x2
#pragma unroll
    for (int kk = 0; kk < 2; kk++)
#pragma unroll
      for (int ot = 0; ot < 4; ot++) {
        const bf16x8 vf = *(const bf16x8*)(
            &Vs[c][(ot * 16 + r16) * 64 + (((kk * 4 + g) ^ (r16 & 7)) * 8)]);
        o[ot] = __builtin_amdgcn_mfma_f32_16x16x32_bf16(vf, pb[kk], o[ot], 0, 0, 0);
      }
    END_BARRIER();
  };

  for (int t = 0; t < NTILES; t += 2) {
    tile(t, 0);
    tile(t + 1, 1);
  }

  asm volatile("s_nop 7\ns_nop 7");  // MFMA->VALU hazard guard before epilogue

  // epilogue: O^T col=q=r16 (same lane as l), row e = ot*16+4g+r
  const float li = 0.125f / ol[0];
  const size_t rowoff = ((size_t)b * Nq + q0 + r16) * Dq + h * 64;
#pragma unroll
  for (int ot = 0; ot < 4; ot++) {
    union { bf16 h[4]; ushort4 u; } r4;
#pragma unroll
    for (int r = 0; r < 4; r++) r4.h[r] = (bf16)(o[ot][r] * li);
    *(ushort4*)(att + rowoff + ot * 16 + 4 * g) = r4.u;
  }
}

// ---------------- LayerNorm over D=512: 4 rows per 256-thr block ----------------
template <bool WB>
__global__ __launch_bounds__(256) void k_ln(const float* __restrict__ in,
                                            const float* __restrict__ gamma,
                                            const float* __restrict__ beta,
                                            float* __restrict__ outf,
                                            bf16* __restrict__ outb) {
  const int row = blockIdx.x * 4 + threadIdx.y;
  const int lane = threadIdx.x;
  const float* p = in + (size_t)row * Dq + lane * 8;
  float4 a = *(const float4*)p;
  float4 c = *(const float4*)(p + 4);
  float vals[8] = {a.x, a.y, a.z, a.w, c.x, c.y, c.z, c.w};
  float s = 0.f, q = 0.f;
#pragma unroll
  for (int j = 0; j < 8; j++) { s += vals[j]; q += vals[j] * vals[j]; }
#pragma unroll
  for (int off = 1; off < 64; off <<= 1) {
    s += __shfl_xor(s, off);
    q += __shfl_xor(q, off);
  }
  float mean = s * (1.f / Dq);
  float var = q * (1.f / Dq) - mean * mean;
  float rstd = rsqrtf(var + 1e-5f);
  float of[8];
#pragma unroll
  for (int j = 0; j < 8; j++) {
    int col = lane * 8 + j;
    of[j] = (vals[j] - mean) * rstd * gamma[col] + beta[col];
  }
  float4* op = (float4*)(outf + (size_t)row * Dq + lane * 8);
  op[0] = make_float4(of[0], of[1], of[2], of[3]);
  op[1] = make_float4(of[4], of[5], of[6], of[7]);
  if (WB) {
    union { bf16 h[8]; ushort4 u[2]; } rr;
#pragma unroll
    for (int j = 0; j < 8; j++) rr.h[j] = (bf16)of[j];
    ushort4* ob = (ushort4*)(outb + (size_t)row * Dq + lane * 8);
    ob[0] = rr.u[0];
    ob[1] = rr.u[1];
  }
}

extern "C" void kernel_launch(void* const* d_in, const int* in_sizes, int n_in,
                              void* d_out, int out_size, void* d_ws, size_t ws_size,
                              hipStream_t stream) {
  const float* x      = (const float*)d_in[0];
  const float* w_qkv  = (const float*)d_in[1];
  const float* b_qkv  = (const float*)d_in[2];
  const float* w_proj = (const float*)d_in[3];
  const float* b_proj = (const float*)d_in[4];
  const float* ln1_g  = (const float*)d_in[5];
  const float* ln1_b  = (const float*)d_in[6];
  const float* w1     = (const float*)d_in[7];
  const float* b1     = (const float*)d_in[8];
  const float* w2     = (const float*)d_in[9];
  const float* b2     = (const float*)d_in[10];
  const float* ln2_g  = (const float*)d_in[11];
  const float* ln2_b  = (const float*)d_in[12];
  float* out = (float*)d_out;

  const int M = Bq * Nq;  // 8192 rows

  char* p = (char*)d_ws;
  auto alloc = [&](size_t bytes) -> void* {
    char* r = p;
    p += (bytes + 255) & ~(size_t)255;
    return (void*)r;
  };
  bf16* xb     = (bf16*)alloc((size_t)M * Dq * 2);        // x bf16; later reused as att
  bf16* qkvb   = (bf16*)alloc((size_t)M * 3 * Dq * 2);
  bf16* wqkvT  = (bf16*)alloc((size_t)3 * Dq * Dq * 2);
  bf16* wprojT = (bf16*)alloc((size_t)Dq * Dq * 2);
  bf16* w1T    = (bf16*)alloc((size_t)Hq * Dq * 2);
  bf16* w2T    = (bf16*)alloc((size_t)Dq * Hq * 2);
  float* y1    = (float*)alloc((size_t)M * Dq * 4);       // also y2
  float* x1f   = (float*)alloc((size_t)M * Dq * 4);
  bf16* x1b    = (bf16*)alloc((size_t)M * Dq * 2);
  bf16* hb     = (bf16*)alloc((size_t)M * Hq * 2);
  bf16* attb   = xb;   // alias: xb consumed by qkv GEMM before attention writes
  bf16* vtb    = hb;   // alias: hb written by ffn1 only after attention is done

  dim3 tb(32, 8);
  k_cvt_bf16<<<(M * Dq / 4 + 255) / 256, 256, 0, stream>>>(x, xb, M * Dq);
  // all 4 weight transposes fused into one dispatch (3072 tiles)
  k_wtrans<<<3072, tb, 0, stream>>>(w_qkv, w_proj, w1, w2, wqkvT, wprojT, w1T, w2T);

  // qkv = x @ w_qkv + b_qkv   (1D grid, XCD-swizzled: GX=12, nwg=768)
  k_gemm<128, false, false, true><<<768, 512, 0, stream>>>(
      xb, wqkvT, b_qkv, nullptr, qkvb, M, 3 * Dq, Dq, 12);
  // vt = plain transpose of V part
  k_vtrans<<<dim3(Nq / 64, Bq * HEADS), 256, 0, stream>>>(qkvb, vtb);
  // attention (QBLK=64: 1024 blocks, 4 blocks/CU)
  k_attn<<<dim3(Bq * HEADS, Nq / 64), 256, 0, stream>>>(qkvb, vtb, attb);
  // y1 = att @ w_proj + b_proj + x   (GX=4, nwg=512)
  k_gemm<64, false, true, false><<<512, 512, 0, stream>>>(
      attb, wprojT, b_proj, x, y1, M, Dq, Dq, 4);
  // x1 = LN1(y1) -> fp32 + bf16   (4 rows/block)
  k_ln<true><<<M / 4, dim3(64, 4), 0, stream>>>(y1, ln1_g, ln1_b, x1f, x1b);
  // h = gelu(x1 @ w1 + b1)   (GX=16, nwg=1024)
  k_gemm<128, true, false, true><<<1024, 512, 0, stream>>>(
      x1b, w1T, b1, nullptr, hb, M, Hq, Dq, 16);
  // y2 = h @ w2 + b2 + x1   (GX=4, nwg=512)
  k_gemm<64, false, true, false><<<512, 512, 0, stream>>>(
      hb, w2T, b2, x1f, y1, M, Dq, Hq, 4);
  // out = LN2(y2)
  k_ln<false><<<M / 4, dim3(64, 4), 0, stream>>>(y1, ln2_g, ln2_b, out, nullptr);
}

// Round 19
// 161.429 us; speedup vs baseline: 1.1461x; 1.0471x over previous
//
#include <hip/hip_runtime.h>

#define HEADS 8
#define Bq 4
#define Nq 2048
#define Dq 512
#define Hq 2048

typedef __bf16 bf16;
typedef __bf16 bf16x8 __attribute__((ext_vector_type(8)));
typedef __bf16 bf16x4 __attribute__((ext_vector_type(4)));
typedef short short4v __attribute__((ext_vector_type(4)));
typedef float f32x4 __attribute__((ext_vector_type(4)));

__device__ __forceinline__ void gload16(const bf16* g, bf16* s) {
  __builtin_amdgcn_global_load_lds(
      (const __attribute__((address_space(1))) void*)g,
      (__attribute__((address_space(3))) void*)s, 16, 0, 0);
}

__device__ __forceinline__ float fexp2(float x) {
#if __has_builtin(__builtin_amdgcn_exp2f)
  return __builtin_amdgcn_exp2f(x);
#else
  return exp2f(x);
#endif
}

__device__ __forceinline__ float frcp(float x) {
#if __has_builtin(__builtin_amdgcn_rcpf)
  return __builtin_amdgcn_rcpf(x);
#else
  return 1.f / x;
#endif
}

// fast GELU: 0.5v(1+tanh(u)) = v*e/(e+1), e=exp(2u)=2^(2u*log2e)
__device__ __forceinline__ float fgelu(float v) {
  float u = 0.7978845608f * (v + 0.044715f * v * v * v);
  float e = fexp2(u * 2.885390082f);
  return v * e * frcp(e + 1.f);
}

// counted-vmcnt barrier pair (attn only — helps there, hurts GEMM per R14 A/B)
#define VM_BARRIER(N)                                         \
  do {                                                        \
    asm volatile("s_waitcnt vmcnt(" #N ")" ::: "memory");     \
    __builtin_amdgcn_s_barrier();                             \
    asm volatile("" ::: "memory");                            \
  } while (0)
#define END_BARRIER()                                         \
  do {                                                        \
    asm volatile("" ::: "memory");                            \
    __builtin_amdgcn_s_barrier();                             \
    asm volatile("" ::: "memory");                            \
  } while (0)

// ---------------- fp32 -> bf16 elementwise convert ----------------
__global__ __launch_bounds__(256) void k_cvt_bf16(const float* __restrict__ in,
                                                  bf16* __restrict__ out, int n) {
  int i = (blockIdx.x * 256 + threadIdx.x) * 4;
  if (i >= n) return;
  float4 v = *(const float4*)(in + i);
  union { bf16 h[4]; ushort4 u; } r;
  r.h[0] = (bf16)v.x; r.h[1] = (bf16)v.y; r.h[2] = (bf16)v.z; r.h[3] = (bf16)v.w;
  *(ushort4*)(out + i) = r.u;
}

// ---------------- fused weight transposes: all 4 weights in ONE dispatch ----------------
__global__ __launch_bounds__(256) void k_wtrans(const float* __restrict__ w_qkv,
                                                const float* __restrict__ w_proj,
                                                const float* __restrict__ w1,
                                                const float* __restrict__ w2,
                                                bf16* __restrict__ wqkvT,
                                                bf16* __restrict__ wprojT,
                                                bf16* __restrict__ w1T,
                                                bf16* __restrict__ w2T) {
  __shared__ float t[32][33];
  const int bid = blockIdx.x;
  const float* src;
  bf16* dst;
  int K, N, n0, k0;
  if (bid < 768) {            // w_qkv: K=512, N=1536 (48 x 16 tiles)
    src = w_qkv; dst = wqkvT; K = 512; N = 1536;
    n0 = (bid % 48) * 32; k0 = (bid / 48) * 32;
  } else if (bid < 1024) {    // w_proj: 512x512 (16 x 16)
    int i = bid - 768;
    src = w_proj; dst = wprojT; K = 512; N = 512;
    n0 = (i % 16) * 32; k0 = (i / 16) * 32;
  } else if (bid < 2048) {    // w1: K=512, N=2048 (64 x 16)
    int i = bid - 1024;
    src = w1; dst = w1T; K = 512; N = 2048;
    n0 = (i % 64) * 32; k0 = (i / 64) * 32;
  } else {                    // w2: K=2048, N=512 (16 x 64)
    int i = bid - 2048;
    src = w2; dst = w2T; K = 2048; N = 512;
    n0 = (i % 16) * 32; k0 = (i / 16) * 32;
  }
  const int tx = threadIdx.x, ty = threadIdx.y;
#pragma unroll
  for (int j = 0; j < 32; j += 8)
    t[ty + j][tx] = src[(size_t)(k0 + ty + j) * N + n0 + tx];
  __syncthreads();
#pragma unroll
  for (int j = 0; j < 32; j += 8)
    dst[(size_t)(n0 + ty + j) * K + k0 + tx] = (bf16)t[tx][ty + j];
}

// ---------------- GEMM: C[M][N] = A[M][K](bf16) * BT[N][K]^T + bias ----------------
// R15-best body + XCD swizzle (R17) + K-loop unroll x2 (literal buffer index
// -> staging/frag addresses constant-fold; R10-proven trick). BM x 128 tile,
// BK=64, 512 threads = 8 waves, global_load_lds staging, double-buffered,
// XOR-swizzled b128 frag reads, ONE __syncthreads per K-step.
template <int BM, bool GELU, bool RESID, bool STORE_BF16>
__global__ __launch_bounds__(512, 4) void k_gemm(const bf16* __restrict__ A,
                                                 const bf16* __restrict__ BT,
                                                 const float* __restrict__ bias,
                                                 const float* __restrict__ resid,
                                                 void* __restrict__ Cout,
                                                 int M, int N, int K, int GX) {
  constexpr int MI = BM / 32;
  constexpr int AROUNDS = BM / 64;
  constexpr size_t MAIN = (size_t)2 * (BM + 128) * 64 * 2;
  constexpr size_t CST = (size_t)BM * 136 * (STORE_BF16 ? 2 : 4);
  constexpr size_t SMEM = MAIN > CST ? MAIN : CST;
  __shared__ __align__(16) char smem[SMEM];
  bf16* Asb = (bf16*)smem;
  bf16* Bsb = Asb + 2 * BM * 64;

  const int nwg = gridDim.x;
  const int id = blockIdx.x;
  const int swz = (id & 7) * (nwg >> 3) + (id >> 3);
  const int bx = swz % GX, by = swz / GX;
  const int m0 = by * BM, n0 = bx * 128;

  const int tid = threadIdx.x, lane = tid & 63, wid = tid >> 6;
  const int wr = wid >> 2, wc = wid & 3;
  const int r16 = lane & 15, g = lane >> 4;
  const int lrow = lane >> 3;
  const int sch = (lane & 7) ^ lrow;

  f32x4 acc[MI][2] = {};

  const int NT = K >> 6;
  auto stage = [&](int t, int buf) {
    const int k0 = t << 6;
#pragma unroll
    for (int i = 0; i < AROUNDS; i++) {
      int row = i * 64 + wid * 8 + lrow;
      gload16(A + (size_t)(m0 + row) * K + k0 + sch * 8,
              Asb + buf * BM * 64 + (i * 64 + wid * 8) * 64);
    }
#pragma unroll
    for (int i = 0; i < 2; i++) {
      int row = i * 64 + wid * 8 + lrow;
      gload16(BT + (size_t)(n0 + row) * K + k0 + sch * 8,
              Bsb + buf * 128 * 64 + (i * 64 + wid * 8) * 64);
    }
  };
  auto compute = [&](const bf16* Ab, const bf16* Bb) {
#pragma unroll
    for (int kk = 0; kk < 2; kk++) {
      bf16x8 af[MI], bfr[2];
#pragma unroll
      for (int mi = 0; mi < MI; mi++)
        af[mi] = *(const bf16x8*)(Ab + (wr * (BM / 2) + mi * 16 + r16) * 64 +
                                  (((kk * 4 + g) ^ (r16 & 7)) * 8));
#pragma unroll
      for (int ni = 0; ni < 2; ni++)
        bfr[ni] = *(const bf16x8*)(Bb + (wc * 32 + ni * 16 + r16) * 64 +
                                   (((kk * 4 + g) ^ (r16 & 7)) * 8));
#pragma unroll
      for (int mi = 0; mi < MI; mi++)
#pragma unroll
        for (int ni = 0; ni < 2; ni++)
          acc[mi][ni] = __builtin_amdgcn_mfma_f32_16x16x32_bf16(af[mi], bfr[ni],
                                                                acc[mi][ni], 0, 0, 0);
    }
  };

  stage(0, 0);
  __syncthreads();

  for (int t = 0; t < NT; t += 2) {
    if (t + 1 < NT) stage(t + 1, 1);
    compute(Asb, Bsb);
    __syncthreads();
    if (t + 2 < NT) stage(t + 2, 0);
    compute(Asb + BM * 64, Bsb + 128 * 64);
    __syncthreads();
  }

  float bv[2];
#pragma unroll
  for (int ni = 0; ni < 2; ni++) bv[ni] = bias[n0 + wc * 32 + ni * 16 + r16];

  if (STORE_BF16) {
    bf16* Cl = (bf16*)smem;
#pragma unroll
    for (int mi = 0; mi < MI; mi++)
#pragma unroll
      for (int ni = 0; ni < 2; ni++)
#pragma unroll
        for (int r = 0; r < 4; r++) {
          float v = acc[mi][ni][r] + bv[ni];
          if (GELU) v = fgelu(v);
          Cl[(wr * (BM / 2) + mi * 16 + 4 * g + r) * 136 + wc * 32 + ni * 16 + r16] =
              (bf16)v;
        }
    __syncthreads();
    constexpr int ROWS_PER = 512 * 8 / 128;  // 32
#pragma unroll
    for (int rr = 0; rr < BM / ROWS_PER; rr++) {
      int row = rr * ROWS_PER + (tid >> 4);
      int cc = (tid & 15) * 8;
      bf16x8 v = *(const bf16x8*)(Cl + row * 136 + cc);
      *(bf16x8*)((bf16*)Cout + (size_t)(m0 + row) * N + n0 + cc) = v;
    }
  } else {
    float* Cl = (float*)smem;
#pragma unroll
    for (int mi = 0; mi < MI; mi++)
#pragma unroll
      for (int ni = 0; ni < 2; ni++)
#pragma unroll
        for (int r = 0; r < 4; r++) {
          float v = acc[mi][ni][r] + bv[ni];
          if (GELU) v = fgelu(v);
          Cl[(wr * (BM / 2) + mi * 16 + 4 * g + r) * 136 + wc * 32 + ni * 16 + r16] = v;
        }
    __syncthreads();
    constexpr int ROWS_PER = 512 * 4 / 128;  // 16
#pragma unroll
    for (int rr = 0; rr < BM / ROWS_PER; rr++) {
      int row = rr * ROWS_PER + (tid >> 5);
      int cc = (tid & 31) * 4;
      f32x4 v = *(const f32x4*)(Cl + row * 136 + cc);
      if (RESID) {
        f32x4 rv = *(const f32x4*)(resid + (size_t)(m0 + row) * N + n0 + cc);
        v += rv;
      }
      *(f32x4*)((float*)Cout + (size_t)(m0 + row) * N + n0 + cc) = v;
    }
  }
}

// ---------------- V transpose (plain): qkvb V-cols -> vt[B*H][64][Nq] ----------------
__global__ __launch_bounds__(256) void k_vtrans(const bf16* __restrict__ qkv,
                                                bf16* __restrict__ vt) {
  __shared__ bf16 T[64 * 66];
  const int kvb = blockIdx.x, bh = blockIdx.y;
  const int b = bh >> 3, h = bh & 7;
  const int tid = threadIdx.x, lane = tid & 63, w = tid >> 6;
  const bf16* src = qkv + ((size_t)b * Nq + kvb * 64) * (3 * Dq) + 2 * Dq + h * 64;
#pragma unroll
  for (int i = 0; i < 2; i++) {
    int u = tid + i * 256;
    int r = u >> 3, ch = u & 7;
    *(int4*)(&T[r * 66 + ch * 8]) = *(const int4*)(src + (size_t)r * (3 * Dq) + ch * 8);
  }
  __syncthreads();
  bf16* dst = vt + (size_t)bh * 64 * Nq + kvb * 64 + lane;
#pragma unroll
  for (int it = 0; it < 16; it++) {
    int e = w * 16 + it;
    dst[(size_t)e * Nq] = T[lane * 66 + e];
  }
}

// ---------------- flash attention: all-K=32 MFMA, no-max exp2 softmax ----------------
// grid (B*H, Nq/64): 4 waves x 16 q-rows, counted-vmcnt schedule, T5 setprio
// around MFMA clusters. K staged with row permutation f via per-lane gload
// SOURCE address; P packs directly into native K=32 B-frags.
__global__ __launch_bounds__(256) void k_attn(const bf16* __restrict__ qkv,
                                              const bf16* __restrict__ vt,
                                              bf16* __restrict__ att) {
  __shared__ bf16 Ks[2][64 * 64];
  __shared__ bf16 Vs[2][64 * 64];
  const int qt = blockIdx.y, b = blockIdx.x >> 3, h = blockIdx.x & 7;
  const int tid = threadIdx.x, lane = tid & 63, wid = tid >> 6;
  const int r16 = lane & 15, g = lane >> 4;
  const size_t base = (size_t)b * Nq * (3 * Dq);
  const bf16* qp = qkv + base + h * 64;
  const bf16* kp = qkv + base + Dq + h * 64;
  const bf16* vtp = vt + (size_t)(b * HEADS + h) * 64 * Nq;
  const int q0 = qt * 64 + wid * 16;

  bf16x8 qf[2];
#pragma unroll
  for (int kk = 0; kk < 2; kk++) {
    bf16x8 q = *(const bf16x8*)(qp + (size_t)(q0 + r16) * (3 * Dq) + kk * 32 + g * 8);
#pragma unroll
    for (int j = 0; j < 8; j++) q[j] = (bf16)((float)q[j] * 1.44269504f);
    qf[kk] = q;
  }

  const int srow = lane >> 3;
  const int sch = (lane & 7) ^ srow;
  int fsrc[2];
#pragma unroll
  for (int i = 0; i < 2; i++) {
    int d = (wid * 2 + i) * 8 + srow;
    fsrc[i] = ((d >> 5) << 5) + 8 * ((d & 15) >> 2) + 4 * ((d >> 4) & 1) + (d & 3);
  }

  bf16x8 ones8;
#pragma unroll
  for (int j = 0; j < 8; j++) ones8[j] = (bf16)1.f;

  f32x4 o[4] = {};
  f32x4 ol = {};

#pragma unroll
  for (int i = 0; i < 2; i++) {
    int br = (wid * 2 + i) * 8;
    gload16(kp + (size_t)fsrc[i] * (3 * Dq) + sch * 8, &Ks[0][br * 64]);
    gload16(vtp + (size_t)(br + srow) * Nq + sch * 8, &Vs[0][br * 64]);
  }
  __syncthreads();

  const int NTILES = Nq / 64;
  auto tile = [&](int t, int c) {
    if (t + 1 < NTILES) {
      const int kv1 = (t + 1) * 64;
#pragma unroll
      for (int i = 0; i < 2; i++) {
        int br = (wid * 2 + i) * 8;
        gload16(kp + (size_t)(kv1 + fsrc[i]) * (3 * Dq) + sch * 8,
                &Ks[c ^ 1][br * 64]);
        gload16(vtp + (size_t)(br + srow) * Nq + kv1 + sch * 8, &Vs[c ^ 1][br * 64]);
      }
      VM_BARRIER(4);
    } else {
      VM_BARRIER(0);
    }

    f32x4 s[4] = {};
    __builtin_amdgcn_s_setprio(1);
#pragma unroll
    for (int kk = 0; kk < 2; kk++)
#pragma unroll
      for (int nt = 0; nt < 4; nt++) {
        const bf16x8 kf = *(const bf16x8*)(
            &Ks[c][(nt * 16 + r16) * 64 + (((4 * kk + g) ^ (r16 & 7)) * 8)]);
        s[nt] = __builtin_amdgcn_mfma_f32_16x16x32_bf16(kf, qf[kk], s[nt], 0, 0, 0);
      }
    __builtin_amdgcn_s_setprio(0);

#pragma unroll
    for (int nt = 0; nt < 4; nt++)
#pragma unroll
      for (int r = 0; r < 4; r++) s[nt][r] = fexp2(s[nt][r]);

    bf16x8 pb[2];
#pragma unroll
    for (int kk = 0; kk < 2; kk++) {
      bf16x8 t8;
#pragma unroll
      for (int r = 0; r < 4; r++) {
        t8[r] = (bf16)s[2 * kk][r];
        t8[4 + r] = (bf16)s[2 * kk + 1][r];
      }
      pb[kk] = t8;
    }

    __builtin_amdgcn_s_setprio(1);
    ol = __builtin_amdgcn_mfma_f32_16x16x32_bf16(ones8, pb[0], ol, 0, 0, 0);
    ol = __builtin_amdgcn_mfma_f32_16x16x32_bf16(ones8, pb[1], ol, 0, 0, 0);
#pragma unroll
    for (int kk = 0; kk < 2; kk++)
#pragma unroll
      for (int ot = 0; ot < 4; ot++) {
        const bf16x8 vf = *(const bf16x8*)(
            &Vs[c][(ot * 16 + r16) * 64 + (((kk * 4 + g) ^ (r16 & 7)) * 8)]);
        o[ot] = __builtin_amdgcn_mfma_f32_16x16x32_bf16(vf, pb[kk], o[ot], 0, 0, 0);
      }
    __builtin_amdgcn_s_setprio(0);
    END_BARRIER();
  };

  for (int t = 0; t < NTILES; t += 2) {
    tile(t, 0);
    tile(t + 1, 1);
  }

  asm volatile("s_nop 7\ns_nop 7");

  const float li = 0.125f / ol[0];
  const size_t rowoff = ((size_t)b * Nq + q0 + r16) * Dq + h * 64;
#pragma unroll
  for (int ot = 0; ot < 4; ot++) {
    union { bf16 h[4]; ushort4 u; } r4;
#pragma unroll
    for (int r = 0; r < 4; r++) r4.h[r] = (bf16)(o[ot][r] * li);
    *(ushort4*)(att + rowoff + ot * 16 + 4 * g) = r4.u;
  }
}

// ---------------- LayerNorm over D=512: 4 rows per 256-thr block ----------------
template <bool WB>
__global__ __launch_bounds__(256) void k_ln(const float* __restrict__ in,
                                            const float* __restrict__ gamma,
                                            const float* __restrict__ beta,
                                            float* __restrict__ outf,
                                            bf16* __restrict__ outb) {
  const int row = blockIdx.x * 4 + threadIdx.y;
  const int lane = threadIdx.x;
  const float* p = in + (size_t)row * Dq + lane * 8;
  float4 a = *(const float4*)p;
  float4 c = *(const float4*)(p + 4);
  float vals[8] = {a.x, a.y, a.z, a.w, c.x, c.y, c.z, c.w};
  float s = 0.f, q = 0.f;
#pragma unroll
  for (int j = 0; j < 8; j++) { s += vals[j]; q += vals[j] * vals[j]; }
#pragma unroll
  for (int off = 1; off < 64; off <<= 1) {
    s += __shfl_xor(s, off);
    q += __shfl_xor(q, off);
  }
  float mean = s * (1.f / Dq);
  float var = q * (1.f / Dq) - mean * mean;
  float rstd = rsqrtf(var + 1e-5f);
  float of[8];
#pragma unroll
  for (int j = 0; j < 8; j++) {
    int col = lane * 8 + j;
    of[j] = (vals[j] - mean) * rstd * gamma[col] + beta[col];
  }
  float4* op = (float4*)(outf + (size_t)row * Dq + lane * 8);
  op[0] = make_float4(of[0], of[1], of[2], of[3]);
  op[1] = make_float4(of[4], of[5], of[6], of[7]);
  if (WB) {
    union { bf16 h[8]; ushort4 u[2]; } rr;
#pragma unroll
    for (int j = 0; j < 8; j++) rr.h[j] = (bf16)of[j];
    ushort4* ob = (ushort4*)(outb + (size_t)row * Dq + lane * 8);
    ob[0] = rr.u[0];
    ob[1] = rr.u[1];
  }
}

extern "C" void kernel_launch(void* const* d_in, const int* in_sizes, int n_in,
                              void* d_out, int out_size, void* d_ws, size_t ws_size,
                              hipStream_t stream) {
  const float* x      = (const float*)d_in[0];
  const float* w_qkv  = (const float*)d_in[1];
  const float* b_qkv  = (const float*)d_in[2];
  const float* w_proj = (const float*)d_in[3];
  const float* b_proj = (const float*)d_in[4];
  const float* ln1_g  = (const float*)d_in[5];
  const float* ln1_b  = (const float*)d_in[6];
  const float* w1     = (const float*)d_in[7];
  const float* b1     = (const float*)d_in[8];
  const float* w2     = (const float*)d_in[9];
  const float* b2     = (const float*)d_in[10];
  const float* ln2_g  = (const float*)d_in[11];
  const float* ln2_b  = (const float*)d_in[12];
  float* out = (float*)d_out;

  const int M = Bq * Nq;  // 8192 rows

  char* p = (char*)d_ws;
  auto alloc = [&](size_t bytes) -> void* {
    char* r = p;
    p += (bytes + 255) & ~(size_t)255;
    return (void*)r;
  };
  bf16* xb     = (bf16*)alloc((size_t)M * Dq * 2);        // x bf16; later reused as att
  bf16* qkvb   = (bf16*)alloc((size_t)M * 3 * Dq * 2);
  bf16* wqkvT  = (bf16*)alloc((size_t)3 * Dq * Dq * 2);
  bf16* wprojT = (bf16*)alloc((size_t)Dq * Dq * 2);
  bf16* w1T    = (bf16*)alloc((size_t)Hq * Dq * 2);
  bf16* w2T    = (bf16*)alloc((size_t)Dq * Hq * 2);
  float* y1    = (float*)alloc((size_t)M * Dq * 4);       // also y2
  float* x1f   = (float*)alloc((size_t)M * Dq * 4);
  bf16* x1b    = (bf16*)alloc((size_t)M * Dq * 2);
  bf16* hb     = (bf16*)alloc((size_t)M * Hq * 2);
  bf16* attb   = xb;   // alias: xb consumed by qkv GEMM before attention writes
  bf16* vtb    = hb;   // alias: hb written by ffn1 only after attention is done

  dim3 tb(32, 8);
  k_cvt_bf16<<<(M * Dq / 4 + 255) / 256, 256, 0, stream>>>(x, xb, M * Dq);
  k_wtrans<<<3072, tb, 0, stream>>>(w_qkv, w_proj, w1, w2, wqkvT, wprojT, w1T, w2T);

  // qkv = x @ w_qkv + b_qkv   (GX=12, nwg=768)
  k_gemm<128, false, false, true><<<768, 512, 0, stream>>>(
      xb, wqkvT, b_qkv, nullptr, qkvb, M, 3 * Dq, Dq, 12);
  // vt = plain transpose of V part
  k_vtrans<<<dim3(Nq / 64, Bq * HEADS), 256, 0, stream>>>(qkvb, vtb);
  // attention
  k_attn<<<dim3(Bq * HEADS, Nq / 64), 256, 0, stream>>>(qkvb, vtb, attb);
  // y1 = att @ w_proj + b_proj + x   (GX=4, nwg=512)
  k_gemm<64, false, true, false><<<512, 512, 0, stream>>>(
      attb, wprojT, b_proj, x, y1, M, Dq, Dq, 4);
  // x1 = LN1(y1) -> fp32 + bf16
  k_ln<true><<<M / 4, dim3(64, 4), 0, stream>>>(y1, ln1_g, ln1_b, x1f, x1b);
  // h = gelu(x1 @ w1 + b1)   (GX=16, nwg=1024)
  k_gemm<128, true, false, true><<<1024, 512, 0, stream>>>(
      x1b, w1T, b1, nullptr, hb, M, Hq, Dq, 16);
  // y2 = h @ w2 + b2 + x1   (GX=4, nwg=512)
  k_gemm<64, false, true, false><<<512, 512, 0, stream>>>(
      hb, w2T, b2, x1f, y1, M, Dq, Hq, 4);
  // out = LN2(y2)
  k_ln<false><<<M / 4, dim3(64, 4), 0, stream>>>(y1, ln2_g, ln2_b, out, nullptr);
}

// Round 20
// 154.529 us; speedup vs baseline: 1.1973x; 1.0447x over previous
//
#include <hip/hip_runtime.h>

#define HEADS 8
#define Bq 4
#define Nq 2048
#define Dq 512
#define Hq 2048

typedef __bf16 bf16;
typedef __bf16 bf16x8 __attribute__((ext_vector_type(8)));
typedef __bf16 bf16x4 __attribute__((ext_vector_type(4)));
typedef short short4v __attribute__((ext_vector_type(4)));
typedef float f32x4 __attribute__((ext_vector_type(4)));

__device__ __forceinline__ void gload16(const bf16* g, bf16* s) {
  __builtin_amdgcn_global_load_lds(
      (const __attribute__((address_space(1))) void*)g,
      (__attribute__((address_space(3))) void*)s, 16, 0, 0);
}

__device__ __forceinline__ float fexp2(float x) {
#if __has_builtin(__builtin_amdgcn_exp2f)
  return __builtin_amdgcn_exp2f(x);
#else
  return exp2f(x);
#endif
}

__device__ __forceinline__ float frcp(float x) {
#if __has_builtin(__builtin_amdgcn_rcpf)
  return __builtin_amdgcn_rcpf(x);
#else
  return 1.f / x;
#endif
}

// fast GELU: 0.5v(1+tanh(u)) = v*e/(e+1), e=exp(2u)=2^(2u*log2e)
__device__ __forceinline__ float fgelu(float v) {
  float u = 0.7978845608f * (v + 0.044715f * v * v * v);
  float e = fexp2(u * 2.885390082f);
  return v * e * frcp(e + 1.f);
}

// counted-vmcnt barrier pair (attn only — helps there, hurts GEMM per R14 A/B)
#define VM_BARRIER(N)                                         \
  do {                                                        \
    asm volatile("s_waitcnt vmcnt(" #N ")" ::: "memory");     \
    __builtin_amdgcn_s_barrier();                             \
    asm volatile("" ::: "memory");                            \
  } while (0)
#define END_BARRIER()                                         \
  do {                                                        \
    asm volatile("" ::: "memory");                            \
    __builtin_amdgcn_s_barrier();                             \
    asm volatile("" ::: "memory");                            \
  } while (0)

// ---------------- fp32 -> bf16 elementwise convert ----------------
__global__ __launch_bounds__(256) void k_cvt_bf16(const float* __restrict__ in,
                                                  bf16* __restrict__ out, int n) {
  int i = (blockIdx.x * 256 + threadIdx.x) * 4;
  if (i >= n) return;
  float4 v = *(const float4*)(in + i);
  union { bf16 h[4]; ushort4 u; } r;
  r.h[0] = (bf16)v.x; r.h[1] = (bf16)v.y; r.h[2] = (bf16)v.z; r.h[3] = (bf16)v.w;
  *(ushort4*)(out + i) = r.u;
}

// ---------------- fused weight transposes: all 4 weights in ONE dispatch ----------------
__global__ __launch_bounds__(256) void k_wtrans(const float* __restrict__ w_qkv,
                                                const float* __restrict__ w_proj,
                                                const float* __restrict__ w1,
                                                const float* __restrict__ w2,
                                                bf16* __restrict__ wqkvT,
                                                bf16* __restrict__ wprojT,
                                                bf16* __restrict__ w1T,
                                                bf16* __restrict__ w2T) {
  __shared__ float t[32][33];
  const int bid = blockIdx.x;
  const float* src;
  bf16* dst;
  int K, N, n0, k0;
  if (bid < 768) {            // w_qkv: K=512, N=1536 (48 x 16 tiles)
    src = w_qkv; dst = wqkvT; K = 512; N = 1536;
    n0 = (bid % 48) * 32; k0 = (bid / 48) * 32;
  } else if (bid < 1024) {    // w_proj: 512x512 (16 x 16)
    int i = bid - 768;
    src = w_proj; dst = wprojT; K = 512; N = 512;
    n0 = (i % 16) * 32; k0 = (i / 16) * 32;
  } else if (bid < 2048) {    // w1: K=512, N=2048 (64 x 16)
    int i = bid - 1024;
    src = w1; dst = w1T; K = 512; N = 2048;
    n0 = (i % 64) * 32; k0 = (i / 64) * 32;
  } else {                    // w2: K=2048, N=512 (16 x 64)
    int i = bid - 2048;
    src = w2; dst = w2T; K = 2048; N = 512;
    n0 = (i % 16) * 32; k0 = (i / 16) * 32;
  }
  const int tx = threadIdx.x, ty = threadIdx.y;
#pragma unroll
  for (int j = 0; j < 32; j += 8)
    t[ty + j][tx] = src[(size_t)(k0 + ty + j) * N + n0 + tx];
  __syncthreads();
#pragma unroll
  for (int j = 0; j < 32; j += 8)
    dst[(size_t)(n0 + ty + j) * K + k0 + tx] = (bf16)t[tx][ty + j];
}

// ---------------- GEMM: C[M][N] = A[M][K](bf16) * BT[N][K]^T + bias ----------------
// R19 body (BK=64, 512 thr, XCD swizzle, K-loop unroll x2). Epilogue variants:
//  - STORE_BF16 && !RESID: bf16 LDS tile -> coalesced 16B stores (+GELU)
//  - STORE_BF16 &&  RESID: float LDS tile -> +fp32 resid -> bf16 8B stores
//  - VTOUT (qkv only): V-blocks (n0>=1024) write TRANSPOSED straight to
//    vt[(b*8+h)*64+e][n] via col-major LDS tile; qkvb write skipped.
template <int BM, bool GELU, bool RESID, bool STORE_BF16, bool VTOUT = false>
__global__ __launch_bounds__(512, 4) void k_gemm(const bf16* __restrict__ A,
                                                 const bf16* __restrict__ BT,
                                                 const float* __restrict__ bias,
                                                 const float* __restrict__ resid,
                                                 void* __restrict__ Cout,
                                                 bf16* __restrict__ vt,
                                                 int M, int N, int K, int GX) {
  constexpr int MI = BM / 32;
  constexpr int AROUNDS = BM / 64;
  constexpr size_t MAIN = (size_t)2 * (BM + 128) * 64 * 2;
  constexpr size_t CST = (size_t)BM * 136 * ((STORE_BF16 && !RESID) ? 2 : 4);
  constexpr size_t SMEM = MAIN > CST ? MAIN : CST;
  __shared__ __align__(16) char smem[SMEM];
  bf16* Asb = (bf16*)smem;
  bf16* Bsb = Asb + 2 * BM * 64;

  const int nwg = gridDim.x;
  const int id = blockIdx.x;
  const int swz = (id & 7) * (nwg >> 3) + (id >> 3);
  const int bx = swz % GX, by = swz / GX;
  const int m0 = by * BM, n0 = bx * 128;

  const int tid = threadIdx.x, lane = tid & 63, wid = tid >> 6;
  const int wr = wid >> 2, wc = wid & 3;
  const int r16 = lane & 15, g = lane >> 4;
  const int lrow = lane >> 3;
  const int sch = (lane & 7) ^ lrow;

  f32x4 acc[MI][2] = {};

  const int NT = K >> 6;
  auto stage = [&](int t, int buf) {
    const int k0 = t << 6;
#pragma unroll
    for (int i = 0; i < AROUNDS; i++) {
      int row = i * 64 + wid * 8 + lrow;
      gload16(A + (size_t)(m0 + row) * K + k0 + sch * 8,
              Asb + buf * BM * 64 + (i * 64 + wid * 8) * 64);
    }
#pragma unroll
    for (int i = 0; i < 2; i++) {
      int row = i * 64 + wid * 8 + lrow;
      gload16(BT + (size_t)(n0 + row) * K + k0 + sch * 8,
              Bsb + buf * 128 * 64 + (i * 64 + wid * 8) * 64);
    }
  };
  auto compute = [&](const bf16* Ab, const bf16* Bb) {
#pragma unroll
    for (int kk = 0; kk < 2; kk++) {
      bf16x8 af[MI], bfr[2];
#pragma unroll
      for (int mi = 0; mi < MI; mi++)
        af[mi] = *(const bf16x8*)(Ab + (wr * (BM / 2) + mi * 16 + r16) * 64 +
                                  (((kk * 4 + g) ^ (r16 & 7)) * 8));
#pragma unroll
      for (int ni = 0; ni < 2; ni++)
        bfr[ni] = *(const bf16x8*)(Bb + (wc * 32 + ni * 16 + r16) * 64 +
                                   (((kk * 4 + g) ^ (r16 & 7)) * 8));
#pragma unroll
      for (int mi = 0; mi < MI; mi++)
#pragma unroll
        for (int ni = 0; ni < 2; ni++)
          acc[mi][ni] = __builtin_amdgcn_mfma_f32_16x16x32_bf16(af[mi], bfr[ni],
                                                                acc[mi][ni], 0, 0, 0);
    }
  };

  stage(0, 0);
  __syncthreads();

  for (int t = 0; t < NT; t += 2) {
    if (t + 1 < NT) stage(t + 1, 1);
    compute(Asb, Bsb);
    __syncthreads();
    if (t + 2 < NT) stage(t + 2, 0);
    compute(Asb + BM * 64, Bsb + 128 * 64);
    __syncthreads();
  }

  float bv[2];
#pragma unroll
  for (int ni = 0; ni < 2; ni++) bv[ni] = bias[n0 + wc * 32 + ni * 16 + r16];

  if (VTOUT && n0 >= 1024) {
    // ---- fused V output: col-major LDS tile -> transposed coalesced stores ----
    bf16* Clt = (bf16*)smem;  // [128 cols][136]
#pragma unroll
    for (int mi = 0; mi < MI; mi++)
#pragma unroll
      for (int ni = 0; ni < 2; ni++)
#pragma unroll
        for (int r = 0; r < 4; r++) {
          float v = acc[mi][ni][r] + bv[ni];
          Clt[(wc * 32 + ni * 16 + r16) * 136 + (wr * 64 + mi * 16 + 4 * g + r)] =
              (bf16)v;
        }
    __syncthreads();
    const int c = tid >> 2, q = tid & 3;
    const int j = (n0 - 1024) >> 7;
    const int h = 2 * j + (c >> 6), e = c & 63;
    const int bb = m0 >> 11, nb = m0 & 2047;
    bf16* dst = vt + ((size_t)(bb * 8 + h) * 64 + e) * Nq + nb + q * 32;
#pragma unroll
    for (int i = 0; i < 4; i++)
      *(int4*)(dst + i * 8) = *(const int4*)(&Clt[c * 136 + q * 32 + i * 8]);
    return;
  }

  if (STORE_BF16 && !RESID) {
    bf16* Cl = (bf16*)smem;
#pragma unroll
    for (int mi = 0; mi < MI; mi++)
#pragma unroll
      for (int ni = 0; ni < 2; ni++)
#pragma unroll
        for (int r = 0; r < 4; r++) {
          float v = acc[mi][ni][r] + bv[ni];
          if (GELU) v = fgelu(v);
          Cl[(wr * (BM / 2) + mi * 16 + 4 * g + r) * 136 + wc * 32 + ni * 16 + r16] =
              (bf16)v;
        }
    __syncthreads();
    constexpr int ROWS_PER = 512 * 8 / 128;  // 32
#pragma unroll
    for (int rr = 0; rr < BM / ROWS_PER; rr++) {
      int row = rr * ROWS_PER + (tid >> 4);
      int cc = (tid & 15) * 8;
      bf16x8 v = *(const bf16x8*)(Cl + row * 136 + cc);
      *(bf16x8*)((bf16*)Cout + (size_t)(m0 + row) * N + n0 + cc) = v;
    }
  } else if (STORE_BF16 && RESID) {
    // float LDS tile + fp32 resid add + bf16 store (single rounding)
    float* Clf = (float*)smem;
#pragma unroll
    for (int mi = 0; mi < MI; mi++)
#pragma unroll
      for (int ni = 0; ni < 2; ni++)
#pragma unroll
        for (int r = 0; r < 4; r++) {
          float v = acc[mi][ni][r] + bv[ni];
          if (GELU) v = fgelu(v);
          Clf[(wr * (BM / 2) + mi * 16 + 4 * g + r) * 136 + wc * 32 + ni * 16 + r16] = v;
        }
    __syncthreads();
    constexpr int ROWS_PER = 512 * 4 / 128;  // 16
#pragma unroll
    for (int rr = 0; rr < BM / ROWS_PER; rr++) {
      int row = rr * ROWS_PER + (tid >> 5);
      int cc = (tid & 31) * 4;
      f32x4 v = *(const f32x4*)(Clf + row * 136 + cc);
      f32x4 rv = *(const f32x4*)(resid + (size_t)(m0 + row) * N + n0 + cc);
      v += rv;
      union { bf16 h[4]; uint2 u; } r4;
#pragma unroll
      for (int r = 0; r < 4; r++) r4.h[r] = (bf16)v[r];
      *(uint2*)((bf16*)Cout + (size_t)(m0 + row) * N + n0 + cc) = r4.u;
    }
  } else {
    float* Cl = (float*)smem;
#pragma unroll
    for (int mi = 0; mi < MI; mi++)
#pragma unroll
      for (int ni = 0; ni < 2; ni++)
#pragma unroll
        for (int r = 0; r < 4; r++) {
          float v = acc[mi][ni][r] + bv[ni];
          if (GELU) v = fgelu(v);
          Cl[(wr * (BM / 2) + mi * 16 + 4 * g + r) * 136 + wc * 32 + ni * 16 + r16] = v;
        }
    __syncthreads();
    constexpr int ROWS_PER = 512 * 4 / 128;  // 16
#pragma unroll
    for (int rr = 0; rr < BM / ROWS_PER; rr++) {
      int row = rr * ROWS_PER + (tid >> 5);
      int cc = (tid & 31) * 4;
      f32x4 v = *(const f32x4*)(Cl + row * 136 + cc);
      if (RESID) {
        f32x4 rv = *(const f32x4*)(resid + (size_t)(m0 + row) * N + n0 + cc);
        v += rv;
      }
      *(f32x4*)((float*)Cout + (size_t)(m0 + row) * N + n0 + cc) = v;
    }
  }
}

// ---------------- flash attention: all-K=32 MFMA, no-max exp2 softmax ----------------
// grid (B*H, Nq/64): 4 waves x 16 q-rows, counted-vmcnt schedule, T5 setprio.
__global__ __launch_bounds__(256) void k_attn(const bf16* __restrict__ qkv,
                                              const bf16* __restrict__ vt,
                                              bf16* __restrict__ att) {
  __shared__ bf16 Ks[2][64 * 64];
  __shared__ bf16 Vs[2][64 * 64];
  const int qt = blockIdx.y, b = blockIdx.x >> 3, h = blockIdx.x & 7;
  const int tid = threadIdx.x, lane = tid & 63, wid = tid >> 6;
  const int r16 = lane & 15, g = lane >> 4;
  const size_t base = (size_t)b * Nq * (3 * Dq);
  const bf16* qp = qkv + base + h * 64;
  const bf16* kp = qkv + base + Dq + h * 64;
  const bf16* vtp = vt + (size_t)(b * HEADS + h) * 64 * Nq;
  const int q0 = qt * 64 + wid * 16;

  bf16x8 qf[2];
#pragma unroll
  for (int kk = 0; kk < 2; kk++) {
    bf16x8 q = *(const bf16x8*)(qp + (size_t)(q0 + r16) * (3 * Dq) + kk * 32 + g * 8);
#pragma unroll
    for (int j = 0; j < 8; j++) q[j] = (bf16)((float)q[j] * 1.44269504f);
    qf[kk] = q;
  }

  const int srow = lane >> 3;
  const int sch = (lane & 7) ^ srow;
  int fsrc[2];
#pragma unroll
  for (int i = 0; i < 2; i++) {
    int d = (wid * 2 + i) * 8 + srow;
    fsrc[i] = ((d >> 5) << 5) + 8 * ((d & 15) >> 2) + 4 * ((d >> 4) & 1) + (d & 3);
  }

  bf16x8 ones8;
#pragma unroll
  for (int j = 0; j < 8; j++) ones8[j] = (bf16)1.f;

  f32x4 o[4] = {};
  f32x4 ol = {};

#pragma unroll
  for (int i = 0; i < 2; i++) {
    int br = (wid * 2 + i) * 8;
    gload16(kp + (size_t)fsrc[i] * (3 * Dq) + sch * 8, &Ks[0][br * 64]);
    gload16(vtp + (size_t)(br + srow) * Nq + sch * 8, &Vs[0][br * 64]);
  }
  __syncthreads();

  const int NTILES = Nq / 64;
  auto tile = [&](int t, int c) {
    if (t + 1 < NTILES) {
      const int kv1 = (t + 1) * 64;
#pragma unroll
      for (int i = 0; i < 2; i++) {
        int br = (wid * 2 + i) * 8;
        gload16(kp + (size_t)(kv1 + fsrc[i]) * (3 * Dq) + sch * 8,
                &Ks[c ^ 1][br * 64]);
        gload16(vtp + (size_t)(br + srow) * Nq + kv1 + sch * 8, &Vs[c ^ 1][br * 64]);
      }
      VM_BARRIER(4);
    } else {
      VM_BARRIER(0);
    }

    f32x4 s[4] = {};
    __builtin_amdgcn_s_setprio(1);
#pragma unroll
    for (int kk = 0; kk < 2; kk++)
#pragma unroll
      for (int nt = 0; nt < 4; nt++) {
        const bf16x8 kf = *(const bf16x8*)(
            &Ks[c][(nt * 16 + r16) * 64 + (((4 * kk + g) ^ (r16 & 7)) * 8)]);
        s[nt] = __builtin_amdgcn_mfma_f32_16x16x32_bf16(kf, qf[kk], s[nt], 0, 0, 0);
      }
    __builtin_amdgcn_s_setprio(0);

#pragma unroll
    for (int nt = 0; nt < 4; nt++)
#pragma unroll
      for (int r = 0; r < 4; r++) s[nt][r] = fexp2(s[nt][r]);

    bf16x8 pb[2];
#pragma unroll
    for (int kk = 0; kk < 2; kk++) {
      bf16x8 t8;
#pragma unroll
      for (int r = 0; r < 4; r++) {
        t8[r] = (bf16)s[2 * kk][r];
        t8[4 + r] = (bf16)s[2 * kk + 1][r];
      }
      pb[kk] = t8;
    }

    __builtin_amdgcn_s_setprio(1);
    ol = __builtin_amdgcn_mfma_f32_16x16x32_bf16(ones8, pb[0], ol, 0, 0, 0);
    ol = __builtin_amdgcn_mfma_f32_16x16x32_bf16(ones8, pb[1], ol, 0, 0, 0);
#pragma unroll
    for (int kk = 0; kk < 2; kk++)
#pragma unroll
      for (int ot = 0; ot < 4; ot++) {
        const bf16x8 vf = *(const bf16x8*)(
            &Vs[c][(ot * 16 + r16) * 64 + (((kk * 4 + g) ^ (r16 & 7)) * 8)]);
        o[ot] = __builtin_amdgcn_mfma_f32_16x16x32_bf16(vf, pb[kk], o[ot], 0, 0, 0);
      }
    __builtin_amdgcn_s_setprio(0);
    END_BARRIER();
  };

  for (int t = 0; t < NTILES; t += 2) {
    tile(t, 0);
    tile(t + 1, 1);
  }

  asm volatile("s_nop 7\ns_nop 7");

  const float li = 0.125f / ol[0];
  const size_t rowoff = ((size_t)b * Nq + q0 + r16) * Dq + h * 64;
#pragma unroll
  for (int ot = 0; ot < 4; ot++) {
    union { bf16 h[4]; ushort4 u; } r4;
#pragma unroll
    for (int r = 0; r < 4; r++) r4.h[r] = (bf16)(o[ot][r] * li);
    *(ushort4*)(att + rowoff + ot * 16 + 4 * g) = r4.u;
  }
}

// ---------------- LayerNorm over D=512 (bf16 input): 4 rows per 256-thr block ----------------
template <bool WB>
__global__ __launch_bounds__(256) void k_ln(const bf16* __restrict__ in,
                                            const float* __restrict__ gamma,
                                            const float* __restrict__ beta,
                                            float* __restrict__ outf,
                                            bf16* __restrict__ outb) {
  const int row = blockIdx.x * 4 + threadIdx.y;
  const int lane = threadIdx.x;
  const bf16* p = in + (size_t)row * Dq + lane * 8;
  bf16x8 a = *(const bf16x8*)p;
  float vals[8];
#pragma unroll
  for (int j = 0; j < 8; j++) vals[j] = (float)a[j];
  float s = 0.f, q = 0.f;
#pragma unroll
  for (int j = 0; j < 8; j++) { s += vals[j]; q += vals[j] * vals[j]; }
#pragma unroll
  for (int off = 1; off < 64; off <<= 1) {
    s += __shfl_xor(s, off);
    q += __shfl_xor(q, off);
  }
  float mean = s * (1.f / Dq);
  float var = q * (1.f / Dq) - mean * mean;
  float rstd = rsqrtf(var + 1e-5f);
  float of[8];
#pragma unroll
  for (int j = 0; j < 8; j++) {
    int col = lane * 8 + j;
    of[j] = (vals[j] - mean) * rstd * gamma[col] + beta[col];
  }
  float4* op = (float4*)(outf + (size_t)row * Dq + lane * 8);
  op[0] = make_float4(of[0], of[1], of[2], of[3]);
  op[1] = make_float4(of[4], of[5], of[6], of[7]);
  if (WB) {
    union { bf16 h[8]; ushort4 u[2]; } rr;
#pragma unroll
    for (int j = 0; j < 8; j++) rr.h[j] = (bf16)of[j];
    ushort4* ob = (ushort4*)(outb + (size_t)row * Dq + lane * 8);
    ob[0] = rr.u[0];
    ob[1] = rr.u[1];
  }
}

extern "C" void kernel_launch(void* const* d_in, const int* in_sizes, int n_in,
                              void* d_out, int out_size, void* d_ws, size_t ws_size,
                              hipStream_t stream) {
  const float* x      = (const float*)d_in[0];
  const float* w_qkv  = (const float*)d_in[1];
  const float* b_qkv  = (const float*)d_in[2];
  const float* w_proj = (const float*)d_in[3];
  const float* b_proj = (const float*)d_in[4];
  const float* ln1_g  = (const float*)d_in[5];
  const float* ln1_b  = (const float*)d_in[6];
  const float* w1     = (const float*)d_in[7];
  const float* b1     = (const float*)d_in[8];
  const float* w2     = (const float*)d_in[9];
  const float* b2     = (const float*)d_in[10];
  const float* ln2_g  = (const float*)d_in[11];
  const float* ln2_b  = (const float*)d_in[12];
  float* out = (float*)d_out;

  const int M = Bq * Nq;  // 8192 rows

  char* p = (char*)d_ws;
  auto alloc = [&](size_t bytes) -> void* {
    char* r = p;
    p += (bytes + 255) & ~(size_t)255;
    return (void*)r;
  };
  bf16* xb     = (bf16*)alloc((size_t)M * Dq * 2);        // x bf16; later reused as att
  bf16* qkvb   = (bf16*)alloc((size_t)M * 3 * Dq * 2);
  bf16* wqkvT  = (bf16*)alloc((size_t)3 * Dq * Dq * 2);
  bf16* wprojT = (bf16*)alloc((size_t)Dq * Dq * 2);
  bf16* w1T    = (bf16*)alloc((size_t)Hq * Dq * 2);
  bf16* w2T    = (bf16*)alloc((size_t)Dq * Hq * 2);
  bf16* y1b    = (bf16*)alloc((size_t)M * Dq * 2);        // bf16 y1 (also y2)
  float* x1f   = (float*)alloc((size_t)M * Dq * 4);
  bf16* x1b    = (bf16*)alloc((size_t)M * Dq * 2);
  bf16* hb     = (bf16*)alloc((size_t)M * Hq * 2);
  bf16* attb   = xb;   // alias: xb consumed by qkv GEMM before attention writes
  bf16* vtb    = hb;   // alias: hb written by ffn1 only after attention is done

  dim3 tb(32, 8);
  k_cvt_bf16<<<(M * Dq / 4 + 255) / 256, 256, 0, stream>>>(x, xb, M * Dq);
  k_wtrans<<<3072, tb, 0, stream>>>(w_qkv, w_proj, w1, w2, wqkvT, wprojT, w1T, w2T);

  // qkv = x @ w_qkv + b_qkv; V part written TRANSPOSED to vtb (GX=12, nwg=768)
  k_gemm<128, false, false, true, true><<<768, 512, 0, stream>>>(
      xb, wqkvT, b_qkv, nullptr, qkvb, vtb, M, 3 * Dq, Dq, 12);
  // attention
  k_attn<<<dim3(Bq * HEADS, Nq / 64), 256, 0, stream>>>(qkvb, vtb, attb);
  // y1 = bf16(att @ w_proj + b_proj + x)   (GX=4, nwg=512)
  k_gemm<64, false, true, true><<<512, 512, 0, stream>>>(
      attb, wprojT, b_proj, x, y1b, nullptr, M, Dq, Dq, 4);
  // x1 = LN1(y1) -> fp32 + bf16
  k_ln<true><<<M / 4, dim3(64, 4), 0, stream>>>(y1b, ln1_g, ln1_b, x1f, x1b);
  // h = gelu(x1 @ w1 + b1)   (GX=16, nwg=1024)
  k_gemm<128, true, false, true><<<1024, 512, 0, stream>>>(
      x1b, w1T, b1, nullptr, hb, nullptr, M, Hq, Dq, 16);
  // y2 = bf16(h @ w2 + b2 + x1)   (GX=4, nwg=512; reuses y1b)
  k_gemm<64, false, true, true><<<512, 512, 0, stream>>>(
      hb, w2T, b2, x1f, y1b, nullptr, M, Dq, Hq, 4);
  // out = LN2(y2)
  k_ln<false><<<M / 4, dim3(64, 4), 0, stream>>>(y1b, ln2_g, ln2_b, out, nullptr);
}

// Round 21
// 148.179 us; speedup vs baseline: 1.2486x; 1.0429x over previous
//
#include <hip/hip_runtime.h>

#define HEADS 8
#define Bq 4
#define Nq 2048
#define Dq 512
#define Hq 2048

typedef __bf16 bf16;
typedef __bf16 bf16x8 __attribute__((ext_vector_type(8)));
typedef __bf16 bf16x4 __attribute__((ext_vector_type(4)));
typedef short short4v __attribute__((ext_vector_type(4)));
typedef float f32x4 __attribute__((ext_vector_type(4)));

__device__ __forceinline__ void gload16(const bf16* g, bf16* s) {
  __builtin_amdgcn_global_load_lds(
      (const __attribute__((address_space(1))) void*)g,
      (__attribute__((address_space(3))) void*)s, 16, 0, 0);
}

__device__ __forceinline__ float fexp2(float x) {
#if __has_builtin(__builtin_amdgcn_exp2f)
  return __builtin_amdgcn_exp2f(x);
#else
  return exp2f(x);
#endif
}

__device__ __forceinline__ float frcp(float x) {
#if __has_builtin(__builtin_amdgcn_rcpf)
  return __builtin_amdgcn_rcpf(x);
#else
  return 1.f / x;
#endif
}

// fast GELU: 0.5v(1+tanh(u)) = v*e/(e+1), e=exp(2u)=2^(2u*log2e)
__device__ __forceinline__ float fgelu(float v) {
  float u = 0.7978845608f * (v + 0.044715f * v * v * v);
  float e = fexp2(u * 2.885390082f);
  return v * e * frcp(e + 1.f);
}

// counted-vmcnt barrier pair (attn only — helps there, hurts GEMM per R14 A/B)
#define VM_BARRIER(N)                                         \
  do {                                                        \
    asm volatile("s_waitcnt vmcnt(" #N ")" ::: "memory");     \
    __builtin_amdgcn_s_barrier();                             \
    asm volatile("" ::: "memory");                            \
  } while (0)
#define END_BARRIER()                                         \
  do {                                                        \
    asm volatile("" ::: "memory");                            \
    __builtin_amdgcn_s_barrier();                             \
    asm volatile("" ::: "memory");                            \
  } while (0)

// ---------------- fused prep: x->bf16 cvt + all 4 weight transposes ----------------
// blocks [0,3072): 32x32 weight transpose tiles; [3072,7168): x cvt (1024 el/blk).
__global__ __launch_bounds__(256) void k_prep(const float* __restrict__ x,
                                              const float* __restrict__ w_qkv,
                                              const float* __restrict__ w_proj,
                                              const float* __restrict__ w1,
                                              const float* __restrict__ w2,
                                              bf16* __restrict__ xb,
                                              bf16* __restrict__ wqkvT,
                                              bf16* __restrict__ wprojT,
                                              bf16* __restrict__ w1T,
                                              bf16* __restrict__ w2T) {
  const int bid = blockIdx.x;
  const int tx = threadIdx.x, ty = threadIdx.y;
  if (bid >= 3072) {
    int i = ((bid - 3072) * 256 + ty * 32 + tx) * 4;
    float4 v = *(const float4*)(x + i);
    union { bf16 h[4]; ushort4 u; } r;
    r.h[0] = (bf16)v.x; r.h[1] = (bf16)v.y; r.h[2] = (bf16)v.z; r.h[3] = (bf16)v.w;
    *(ushort4*)(xb + i) = r.u;
    return;
  }
  __shared__ float t[32][33];
  const float* src;
  bf16* dst;
  int K, N, n0, k0;
  if (bid < 768) {            // w_qkv: K=512, N=1536 (48 x 16 tiles)
    src = w_qkv; dst = wqkvT; K = 512; N = 1536;
    n0 = (bid % 48) * 32; k0 = (bid / 48) * 32;
  } else if (bid < 1024) {    // w_proj: 512x512 (16 x 16)
    int i = bid - 768;
    src = w_proj; dst = wprojT; K = 512; N = 512;
    n0 = (i % 16) * 32; k0 = (i / 16) * 32;
  } else if (bid < 2048) {    // w1: K=512, N=2048 (64 x 16)
    int i = bid - 1024;
    src = w1; dst = w1T; K = 512; N = 2048;
    n0 = (i % 64) * 32; k0 = (i / 64) * 32;
  } else {                    // w2: K=2048, N=512 (16 x 64)
    int i = bid - 2048;
    src = w2; dst = w2T; K = 2048; N = 512;
    n0 = (i % 16) * 32; k0 = (i / 16) * 32;
  }
#pragma unroll
  for (int j = 0; j < 32; j += 8)
    t[ty + j][tx] = src[(size_t)(k0 + ty + j) * N + n0 + tx];
  __syncthreads();
#pragma unroll
  for (int j = 0; j < 32; j += 8)
    dst[(size_t)(n0 + ty + j) * K + k0 + tx] = (bf16)t[tx][ty + j];
}

// ---------------- GEMM: C[M][N] = A[M][K](bf16) * BT[N][K]^T + bias ----------------
// R19 body (BK=64, 512 thr, XCD swizzle, K-loop unroll x2). RES: 0=none,
// 1=fp32 resid, 2=bf16 resid. Epilogues as R20 + bf16-resid variant.
template <int BM, bool GELU, int RES, bool STORE_BF16, bool VTOUT = false>
__global__ __launch_bounds__(512, 4) void k_gemm(const bf16* __restrict__ A,
                                                 const bf16* __restrict__ BT,
                                                 const float* __restrict__ bias,
                                                 const void* __restrict__ resid,
                                                 void* __restrict__ Cout,
                                                 bf16* __restrict__ vt,
                                                 int M, int N, int K, int GX) {
  constexpr int MI = BM / 32;
  constexpr int AROUNDS = BM / 64;
  constexpr size_t MAIN = (size_t)2 * (BM + 128) * 64 * 2;
  constexpr size_t CST = (size_t)BM * 136 * ((STORE_BF16 && RES == 0) ? 2 : 4);
  constexpr size_t SMEM = MAIN > CST ? MAIN : CST;
  __shared__ __align__(16) char smem[SMEM];
  bf16* Asb = (bf16*)smem;
  bf16* Bsb = Asb + 2 * BM * 64;

  const int nwg = gridDim.x;
  const int id = blockIdx.x;
  const int swz = (id & 7) * (nwg >> 3) + (id >> 3);
  const int bx = swz % GX, by = swz / GX;
  const int m0 = by * BM, n0 = bx * 128;

  const int tid = threadIdx.x, lane = tid & 63, wid = tid >> 6;
  const int wr = wid >> 2, wc = wid & 3;
  const int r16 = lane & 15, g = lane >> 4;
  const int lrow = lane >> 3;
  const int sch = (lane & 7) ^ lrow;

  f32x4 acc[MI][2] = {};

  const int NT = K >> 6;
  auto stage = [&](int t, int buf) {
    const int k0 = t << 6;
#pragma unroll
    for (int i = 0; i < AROUNDS; i++) {
      int row = i * 64 + wid * 8 + lrow;
      gload16(A + (size_t)(m0 + row) * K + k0 + sch * 8,
              Asb + buf * BM * 64 + (i * 64 + wid * 8) * 64);
    }
#pragma unroll
    for (int i = 0; i < 2; i++) {
      int row = i * 64 + wid * 8 + lrow;
      gload16(BT + (size_t)(n0 + row) * K + k0 + sch * 8,
              Bsb + buf * 128 * 64 + (i * 64 + wid * 8) * 64);
    }
  };
  auto compute = [&](const bf16* Ab, const bf16* Bb) {
#pragma unroll
    for (int kk = 0; kk < 2; kk++) {
      bf16x8 af[MI], bfr[2];
#pragma unroll
      for (int mi = 0; mi < MI; mi++)
        af[mi] = *(const bf16x8*)(Ab + (wr * (BM / 2) + mi * 16 + r16) * 64 +
                                  (((kk * 4 + g) ^ (r16 & 7)) * 8));
#pragma unroll
      for (int ni = 0; ni < 2; ni++)
        bfr[ni] = *(const bf16x8*)(Bb + (wc * 32 + ni * 16 + r16) * 64 +
                                   (((kk * 4 + g) ^ (r16 & 7)) * 8));
#pragma unroll
      for (int mi = 0; mi < MI; mi++)
#pragma unroll
        for (int ni = 0; ni < 2; ni++)
          acc[mi][ni] = __builtin_amdgcn_mfma_f32_16x16x32_bf16(af[mi], bfr[ni],
                                                                acc[mi][ni], 0, 0, 0);
    }
  };

  stage(0, 0);
  __syncthreads();

  for (int t = 0; t < NT; t += 2) {
    if (t + 1 < NT) stage(t + 1, 1);
    compute(Asb, Bsb);
    __syncthreads();
    if (t + 2 < NT) stage(t + 2, 0);
    compute(Asb + BM * 64, Bsb + 128 * 64);
    __syncthreads();
  }

  float bv[2];
#pragma unroll
  for (int ni = 0; ni < 2; ni++) bv[ni] = bias[n0 + wc * 32 + ni * 16 + r16];

  if (VTOUT && n0 >= 1024) {
    // ---- fused V output: col-major LDS tile -> transposed coalesced stores ----
    bf16* Clt = (bf16*)smem;  // [128 cols][136]
#pragma unroll
    for (int mi = 0; mi < MI; mi++)
#pragma unroll
      for (int ni = 0; ni < 2; ni++)
#pragma unroll
        for (int r = 0; r < 4; r++) {
          float v = acc[mi][ni][r] + bv[ni];
          Clt[(wc * 32 + ni * 16 + r16) * 136 + (wr * 64 + mi * 16 + 4 * g + r)] =
              (bf16)v;
        }
    __syncthreads();
    const int c = tid >> 2, q = tid & 3;
    const int j = (n0 - 1024) >> 7;
    const int h = 2 * j + (c >> 6), e = c & 63;
    const int bb = m0 >> 11, nb = m0 & 2047;
    bf16* dst = vt + ((size_t)(bb * 8 + h) * 64 + e) * Nq + nb + q * 32;
#pragma unroll
    for (int i = 0; i < 4; i++)
      *(int4*)(dst + i * 8) = *(const int4*)(&Clt[c * 136 + q * 32 + i * 8]);
    return;
  }

  if (STORE_BF16 && RES == 0) {
    bf16* Cl = (bf16*)smem;
#pragma unroll
    for (int mi = 0; mi < MI; mi++)
#pragma unroll
      for (int ni = 0; ni < 2; ni++)
#pragma unroll
        for (int r = 0; r < 4; r++) {
          float v = acc[mi][ni][r] + bv[ni];
          if (GELU) v = fgelu(v);
          Cl[(wr * (BM / 2) + mi * 16 + 4 * g + r) * 136 + wc * 32 + ni * 16 + r16] =
              (bf16)v;
        }
    __syncthreads();
    constexpr int ROWS_PER = 512 * 8 / 128;  // 32
#pragma unroll
    for (int rr = 0; rr < BM / ROWS_PER; rr++) {
      int row = rr * ROWS_PER + (tid >> 4);
      int cc = (tid & 15) * 8;
      bf16x8 v = *(const bf16x8*)(Cl + row * 136 + cc);
      *(bf16x8*)((bf16*)Cout + (size_t)(m0 + row) * N + n0 + cc) = v;
    }
  } else if (STORE_BF16) {
    // float LDS tile + resid add (fp32 or bf16) + bf16 store (single rounding)
    float* Clf = (float*)smem;
#pragma unroll
    for (int mi = 0; mi < MI; mi++)
#pragma unroll
      for (int ni = 0; ni < 2; ni++)
#pragma unroll
        for (int r = 0; r < 4; r++) {
          float v = acc[mi][ni][r] + bv[ni];
          if (GELU) v = fgelu(v);
          Clf[(wr * (BM / 2) + mi * 16 + 4 * g + r) * 136 + wc * 32 + ni * 16 + r16] = v;
        }
    __syncthreads();
    constexpr int ROWS_PER = 512 * 4 / 128;  // 16
#pragma unroll
    for (int rr = 0; rr < BM / ROWS_PER; rr++) {
      int row = rr * ROWS_PER + (tid >> 5);
      int cc = (tid & 31) * 4;
      f32x4 v = *(const f32x4*)(Clf + row * 136 + cc);
      if (RES == 1) {
        f32x4 rv = *(const f32x4*)((const float*)resid + (size_t)(m0 + row) * N + n0 + cc);
        v += rv;
      } else {
        bf16x4 rb = *(const bf16x4*)((const bf16*)resid + (size_t)(m0 + row) * N + n0 + cc);
#pragma unroll
        for (int r = 0; r < 4; r++) v[r] += (float)rb[r];
      }
      union { bf16 h[4]; uint2 u; } r4;
#pragma unroll
      for (int r = 0; r < 4; r++) r4.h[r] = (bf16)v[r];
      *(uint2*)((bf16*)Cout + (size_t)(m0 + row) * N + n0 + cc) = r4.u;
    }
  } else {
    float* Cl = (float*)smem;
#pragma unroll
    for (int mi = 0; mi < MI; mi++)
#pragma unroll
      for (int ni = 0; ni < 2; ni++)
#pragma unroll
        for (int r = 0; r < 4; r++) {
          float v = acc[mi][ni][r] + bv[ni];
          if (GELU) v = fgelu(v);
          Cl[(wr * (BM / 2) + mi * 16 + 4 * g + r) * 136 + wc * 32 + ni * 16 + r16] = v;
        }
    __syncthreads();
    constexpr int ROWS_PER = 512 * 4 / 128;  // 16
#pragma unroll
    for (int rr = 0; rr < BM / ROWS_PER; rr++) {
      int row = rr * ROWS_PER + (tid >> 5);
      int cc = (tid & 31) * 4;
      f32x4 v = *(const f32x4*)(Cl + row * 136 + cc);
      if (RES == 1) {
        f32x4 rv = *(const f32x4*)((const float*)resid + (size_t)(m0 + row) * N + n0 + cc);
        v += rv;
      }
      *(f32x4*)((float*)Cout + (size_t)(m0 + row) * N + n0 + cc) = v;
    }
  }
}

// ---------------- flash attention: all-K=32 MFMA, no-max exp2 softmax ----------------
// grid (B*H, Nq/64): 4 waves x 16 q-rows, counted-vmcnt schedule, T5 setprio.
__global__ __launch_bounds__(256) void k_attn(const bf16* __restrict__ qkv,
                                              const bf16* __restrict__ vt,
                                              bf16* __restrict__ att) {
  __shared__ bf16 Ks[2][64 * 64];
  __shared__ bf16 Vs[2][64 * 64];
  const int qt = blockIdx.y, b = blockIdx.x >> 3, h = blockIdx.x & 7;
  const int tid = threadIdx.x, lane = tid & 63, wid = tid >> 6;
  const int r16 = lane & 15, g = lane >> 4;
  const size_t base = (size_t)b * Nq * (3 * Dq);
  const bf16* qp = qkv + base + h * 64;
  const bf16* kp = qkv + base + Dq + h * 64;
  const bf16* vtp = vt + (size_t)(b * HEADS + h) * 64 * Nq;
  const int q0 = qt * 64 + wid * 16;

  bf16x8 qf[2];
#pragma unroll
  for (int kk = 0; kk < 2; kk++) {
    bf16x8 q = *(const bf16x8*)(qp + (size_t)(q0 + r16) * (3 * Dq) + kk * 32 + g * 8);
#pragma unroll
    for (int j = 0; j < 8; j++) q[j] = (bf16)((float)q[j] * 1.44269504f);
    qf[kk] = q;
  }

  const int srow = lane >> 3;
  const int sch = (lane & 7) ^ srow;
  int fsrc[2];
#pragma unroll
  for (int i = 0; i < 2; i++) {
    int d = (wid * 2 + i) * 8 + srow;
    fsrc[i] = ((d >> 5) << 5) + 8 * ((d & 15) >> 2) + 4 * ((d >> 4) & 1) + (d & 3);
  }

  bf16x8 ones8;
#pragma unroll
  for (int j = 0; j < 8; j++) ones8[j] = (bf16)1.f;

  f32x4 o[4] = {};
  f32x4 ol = {};

#pragma unroll
  for (int i = 0; i < 2; i++) {
    int br = (wid * 2 + i) * 8;
    gload16(kp + (size_t)fsrc[i] * (3 * Dq) + sch * 8, &Ks[0][br * 64]);
    gload16(vtp + (size_t)(br + srow) * Nq + sch * 8, &Vs[0][br * 64]);
  }
  __syncthreads();

  const int NTILES = Nq / 64;
  auto tile = [&](int t, int c) {
    if (t + 1 < NTILES) {
      const int kv1 = (t + 1) * 64;
#pragma unroll
      for (int i = 0; i < 2; i++) {
        int br = (wid * 2 + i) * 8;
        gload16(kp + (size_t)(kv1 + fsrc[i]) * (3 * Dq) + sch * 8,
                &Ks[c ^ 1][br * 64]);
        gload16(vtp + (size_t)(br + srow) * Nq + kv1 + sch * 8, &Vs[c ^ 1][br * 64]);
      }
      VM_BARRIER(4);
    } else {
      VM_BARRIER(0);
    }

    f32x4 s[4] = {};
    __builtin_amdgcn_s_setprio(1);
#pragma unroll
    for (int kk = 0; kk < 2; kk++)
#pragma unroll
      for (int nt = 0; nt < 4; nt++) {
        const bf16x8 kf = *(const bf16x8*)(
            &Ks[c][(nt * 16 + r16) * 64 + (((4 * kk + g) ^ (r16 & 7)) * 8)]);
        s[nt] = __builtin_amdgcn_mfma_f32_16x16x32_bf16(kf, qf[kk], s[nt], 0, 0, 0);
      }
    __builtin_amdgcn_s_setprio(0);

#pragma unroll
    for (int nt = 0; nt < 4; nt++)
#pragma unroll
      for (int r = 0; r < 4; r++) s[nt][r] = fexp2(s[nt][r]);

    bf16x8 pb[2];
#pragma unroll
    for (int kk = 0; kk < 2; kk++) {
      bf16x8 t8;
#pragma unroll
      for (int r = 0; r < 4; r++) {
        t8[r] = (bf16)s[2 * kk][r];
        t8[4 + r] = (bf16)s[2 * kk + 1][r];
      }
      pb[kk] = t8;
    }

    __builtin_amdgcn_s_setprio(1);
    ol = __builtin_amdgcn_mfma_f32_16x16x32_bf16(ones8, pb[0], ol, 0, 0, 0);
    ol = __builtin_amdgcn_mfma_f32_16x16x32_bf16(ones8, pb[1], ol, 0, 0, 0);
#pragma unroll
    for (int kk = 0; kk < 2; kk++)
#pragma unroll
      for (int ot = 0; ot < 4; ot++) {
        const bf16x8 vf = *(const bf16x8*)(
            &Vs[c][(ot * 16 + r16) * 64 + (((kk * 4 + g) ^ (r16 & 7)) * 8)]);
        o[ot] = __builtin_amdgcn_mfma_f32_16x16x32_bf16(vf, pb[kk], o[ot], 0, 0, 0);
      }
    __builtin_amdgcn_s_setprio(0);
    END_BARRIER();
  };

  for (int t = 0; t < NTILES; t += 2) {
    tile(t, 0);
    tile(t + 1, 1);
  }

  asm volatile("s_nop 7\ns_nop 7");

  const float li = 0.125f / ol[0];
  const size_t rowoff = ((size_t)b * Nq + q0 + r16) * Dq + h * 64;
#pragma unroll
  for (int ot = 0; ot < 4; ot++) {
    union { bf16 h[4]; ushort4 u; } r4;
#pragma unroll
    for (int r = 0; r < 4; r++) r4.h[r] = (bf16)(o[ot][r] * li);
    *(ushort4*)(att + rowoff + ot * 16 + 4 * g) = r4.u;
  }
}

// ---------------- LayerNorm over D=512 (bf16 input): 4 rows per 256-thr block ----------------
template <bool WF, bool WB>
__global__ __launch_bounds__(256) void k_ln(const bf16* __restrict__ in,
                                            const float* __restrict__ gamma,
                                            const float* __restrict__ beta,
                                            float* __restrict__ outf,
                                            bf16* __restrict__ outb) {
  const int row = blockIdx.x * 4 + threadIdx.y;
  const int lane = threadIdx.x;
  const bf16* p = in + (size_t)row * Dq + lane * 8;
  bf16x8 a = *(const bf16x8*)p;
  float vals[8];
#pragma unroll
  for (int j = 0; j < 8; j++) vals[j] = (float)a[j];
  float s = 0.f, q = 0.f;
#pragma unroll
  for (int j = 0; j < 8; j++) { s += vals[j]; q += vals[j] * vals[j]; }
#pragma unroll
  for (int off = 1; off < 64; off <<= 1) {
    s += __shfl_xor(s, off);
    q += __shfl_xor(q, off);
  }
  float mean = s * (1.f / Dq);
  float var = q * (1.f / Dq) - mean * mean;
  float rstd = rsqrtf(var + 1e-5f);
  float of[8];
#pragma unroll
  for (int j = 0; j < 8; j++) {
    int col = lane * 8 + j;
    of[j] = (vals[j] - mean) * rstd * gamma[col] + beta[col];
  }
  if (WF) {
    float4* op = (float4*)(outf + (size_t)row * Dq + lane * 8);
    op[0] = make_float4(of[0], of[1], of[2], of[3]);
    op[1] = make_float4(of[4], of[5], of[6], of[7]);
  }
  if (WB) {
    union { bf16 h[8]; ushort4 u[2]; } rr;
#pragma unroll
    for (int j = 0; j < 8; j++) rr.h[j] = (bf16)of[j];
    ushort4* ob = (ushort4*)(outb + (size_t)row * Dq + lane * 8);
    ob[0] = rr.u[0];
    ob[1] = rr.u[1];
  }
}

extern "C" void kernel_launch(void* const* d_in, const int* in_sizes, int n_in,
                              void* d_out, int out_size, void* d_ws, size_t ws_size,
                              hipStream_t stream) {
  const float* x      = (const float*)d_in[0];
  const float* w_qkv  = (const float*)d_in[1];
  const float* b_qkv  = (const float*)d_in[2];
  const float* w_proj = (const float*)d_in[3];
  const float* b_proj = (const float*)d_in[4];
  const float* ln1_g  = (const float*)d_in[5];
  const float* ln1_b  = (const float*)d_in[6];
  const float* w1     = (const float*)d_in[7];
  const float* b1     = (const float*)d_in[8];
  const float* w2     = (const float*)d_in[9];
  const float* b2     = (const float*)d_in[10];
  const float* ln2_g  = (const float*)d_in[11];
  const float* ln2_b  = (const float*)d_in[12];
  float* out = (float*)d_out;

  const int M = Bq * Nq;  // 8192 rows

  char* p = (char*)d_ws;
  auto alloc = [&](size_t bytes) -> void* {
    char* r = p;
    p += (bytes + 255) & ~(size_t)255;
    return (void*)r;
  };
  bf16* xb     = (bf16*)alloc((size_t)M * Dq * 2);        // x bf16; later reused as att
  bf16* qkvb   = (bf16*)alloc((size_t)M * 3 * Dq * 2);
  bf16* wqkvT  = (bf16*)alloc((size_t)3 * Dq * Dq * 2);
  bf16* wprojT = (bf16*)alloc((size_t)Dq * Dq * 2);
  bf16* w1T    = (bf16*)alloc((size_t)Hq * Dq * 2);
  bf16* w2T    = (bf16*)alloc((size_t)Dq * Hq * 2);
  bf16* y1b    = (bf16*)alloc((size_t)M * Dq * 2);        // bf16 y1 (also y2)
  bf16* x1b    = (bf16*)alloc((size_t)M * Dq * 2);
  bf16* hb     = (bf16*)alloc((size_t)M * Hq * 2);
  bf16* attb   = xb;   // alias: xb consumed by qkv GEMM before attention writes
  bf16* vtb    = hb;   // alias: hb written by ffn1 only after attention is done

  dim3 tb(32, 8);
  // prep: x cvt + all 4 weight transposes in ONE dispatch
  k_prep<<<7168, tb, 0, stream>>>(x, w_qkv, w_proj, w1, w2, xb, wqkvT, wprojT,
                                  w1T, w2T);

  // qkv = x @ w_qkv + b_qkv; V part written TRANSPOSED to vtb (GX=12, nwg=768)
  k_gemm<128, false, 0, true, true><<<768, 512, 0, stream>>>(
      xb, wqkvT, b_qkv, nullptr, qkvb, vtb, M, 3 * Dq, Dq, 12);
  // attention
  k_attn<<<dim3(Bq * HEADS, Nq / 64), 256, 0, stream>>>(qkvb, vtb, attb);
  // y1 = bf16(att @ w_proj + b_proj + x)   (GX=4, nwg=512; fp32 resid)
  k_gemm<64, false, 1, true><<<512, 512, 0, stream>>>(
      attb, wprojT, b_proj, x, y1b, nullptr, M, Dq, Dq, 4);
  // x1 = LN1(y1) -> bf16 only
  k_ln<false, true><<<M / 4, dim3(64, 4), 0, stream>>>(y1b, ln1_g, ln1_b,
                                                       nullptr, x1b);
  // h = gelu(x1 @ w1 + b1)   (GX=16, nwg=1024)
  k_gemm<128, true, 0, true><<<1024, 512, 0, stream>>>(
      x1b, w1T, b1, nullptr, hb, nullptr, M, Hq, Dq, 16);
  // y2 = bf16(h @ w2 + b2 + x1)   (GX=4, nwg=512; bf16 resid = x1b)
  k_gemm<64, false, 2, true><<<512, 512, 0, stream>>>(
      hb, w2T, b2, x1b, y1b, nullptr, M, Dq, Hq, 4);
  // out = LN2(y2) -> fp32
  k_ln<true, false><<<M / 4, dim3(64, 4), 0, stream>>>(y1b, ln2_g, ln2_b, out,
                                                       nullptr);
}